// Round 4
// baseline (382.340 us; speedup 1.0000x reference)
//
#include <hip/hip_runtime.h>
#include <math.h>

// Problem constants: N=100000, E=1600000, D_IN=D_OUT=128
#define D 128
#define BSHIFT 9              // 512 dst rows per bucket
#define BROWS 512
#define TILE 8192             // edges per binA workgroup
constexpr float BN_EPS = 1e-5f;
typedef unsigned long long ull;

// bf16 helpers (manual, RNE) ------------------------------------------------
__device__ __forceinline__ unsigned f2bf_rne(float f) {
    unsigned u = __float_as_uint(f);
    return (u + 0x7FFFu + ((u >> 16) & 1u)) >> 16;
}
__device__ __forceinline__ float bf_lo(unsigned u) { return __uint_as_float(u << 16); }
__device__ __forceinline__ float bf_hi(unsigned u) { return __uint_as_float(u & 0xFFFF0000u); }

// ---------------------------------------------------------------------------
// phase1: fused dispatch. Blocks [0,nwgA) run binA (bucket sort pass A);
// blocks [nwgA, nwgA+ngemm) run gemm_pack (y = x@W, packed to bf16).
//
// Round-4 change: W is no longer staged in LDS. W is 64 KB and L2-resident
// (every block reads it -> broadcast); staging it cost 64 KB LDS -> 80 KB
// footprint -> 2 blocks/CU -> 2 waves/SIMD, starving the VALU loop. Now LDS
// is 16 KB (sA only) -> 8 blocks/CU -> 8 waves/SIMD for the same math.
// ---------------------------------------------------------------------------
__global__ __launch_bounds__(256) void phase1_kernel(
    const float* __restrict__ A,
    const float* __restrict__ W,
    unsigned* __restrict__ yb,
    int n,
    const int* __restrict__ esrc, const int* __restrict__ edst,
    const float* __restrict__ evals,
    uint2* __restrict__ slices,        // [nwgA * TILE]
    int* __restrict__ ofs_t,           // [(B+1) * nwgA], transposed [bucket][wg]
    int B, int nwgA, int E)
{
    __shared__ __align__(16) char smem[16384];
    const int tid = threadIdx.x;

    if ((int)blockIdx.x < nwgA) {
        // ------------------- binA: coarse bucket sort -------------------
        int* h   = (int*)smem;
        int* ps  = h + 256;
        int* cur = ps + 256;
        const int wg = blockIdx.x;
        const int e0 = wg * TILE;
        const int e1 = min(e0 + TILE, E);

        h[tid] = 0;
        __syncthreads();
        for (int e = e0 + tid; e < e1; e += 256)
            atomicAdd(&h[edst[e] >> BSHIFT], 1);
        __syncthreads();

        const int v = h[tid];
        ps[tid] = v;
        __syncthreads();
        for (int off = 1; off < 256; off <<= 1) {
            int t = (tid >= off) ? ps[tid - off] : 0;
            __syncthreads();
            if (tid >= off) ps[tid] += t;
            __syncthreads();
        }
        const int excl = ps[tid] - v;
        if (tid < B) {
            cur[tid] = excl;
            ofs_t[(size_t)tid * nwgA + wg] = excl;
        }
        if (tid == 0) ofs_t[(size_t)B * nwgA + wg] = e1 - e0;  // sentinel
        __syncthreads();

        uint2* slice = slices + (size_t)wg * TILE;
        for (int e = e0 + tid; e < e1; e += 256) {
            int d = edst[e];
            int b = d >> BSHIFT;
            int p = atomicAdd(&cur[b], 1);
            uint2 rec;
            rec.x = (unsigned)(d & (BROWS - 1)) | ((unsigned)esrc[e] << BSHIFT);
            rec.y = __float_as_uint(evals[e]);
            slice[p] = rec;
        }
    } else {
        // ------------------- gemm_pack: y = x@W -> bf16 -------------------
        float (*sA)[128] = (float(*)[128])smem;            // 16 KB

        const int row0 = (blockIdx.x - nwgA) * 32;
        const float4* A4  = (const float4*)(A + (size_t)row0 * D);
        float4*       sA4 = (float4*)&sA[0][0];
#pragma unroll
        for (int i = 0; i < 4; i++) {
            int idx = tid + 256 * i;
            sA4[idx] = ((size_t)row0 * D + (size_t)idx * 4 < (size_t)n * D)
                           ? A4[idx] : make_float4(0.f, 0.f, 0.f, 0.f);
        }
        __syncthreads();

        const int tx = tid & 31;
        const int ty = tid >> 5;
        const int c0 = tx * 4;
        const float4* W4 = (const float4*)W;   // global, L2-broadcast

        float acc[4][4] = {};
        for (int k0 = 0; k0 < 128; k0 += 4) {
            float4 a[4];
#pragma unroll
            for (int j = 0; j < 4; j++)
                a[j] = *(const float4*)&sA[ty + 8 * j][k0];
#pragma unroll
            for (int kk = 0; kk < 4; kk++) {
                const float4 w = W4[(k0 + kk) * 32 + tx];
                const float ak[4] = { kk == 0 ? a[0].x : kk == 1 ? a[0].y : kk == 2 ? a[0].z : a[0].w,
                                      kk == 0 ? a[1].x : kk == 1 ? a[1].y : kk == 2 ? a[1].z : a[1].w,
                                      kk == 0 ? a[2].x : kk == 1 ? a[2].y : kk == 2 ? a[2].z : a[2].w,
                                      kk == 0 ? a[3].x : kk == 1 ? a[3].y : kk == 2 ? a[3].z : a[3].w };
#pragma unroll
                for (int j = 0; j < 4; j++) {
                    acc[j][0] += ak[j] * w.x;
                    acc[j][1] += ak[j] * w.y;
                    acc[j][2] += ak[j] * w.z;
                    acc[j][3] += ak[j] * w.w;
                }
            }
        }

#pragma unroll
        for (int j = 0; j < 4; j++) {
            const int row = row0 + ty + 8 * j;
            if (row < n) {
                uint2 o;
                o.x = f2bf_rne(acc[j][0]) | (f2bf_rne(acc[j][1]) << 16);
                o.y = f2bf_rne(acc[j][2]) | (f2bf_rne(acc[j][3]) << 16);
                ((uint2*)(yb + (size_t)row * 64))[tx] = o;
            }
        }
    }
}

// ---------------------------------------------------------------------------
// binB: one 1024-thread wg (16 waves) per bucket.
// ---------------------------------------------------------------------------
__global__ __launch_bounds__(1024) void binB_kernel(
    const uint2* __restrict__ slices,
    const int* __restrict__ ofs_t,
    int* __restrict__ rowptr,          // [n], end-form
    ull* __restrict__ csr,             // [E]
    int B, int nwgA, int n)
{
    __shared__ int srow[256];
    __shared__ int erow[256];
    __shared__ int red[256];
    __shared__ int hist[BROWS];
    __shared__ int curs[BROWS];
    __shared__ int ps[BROWS];
    __shared__ int s_bbase;

    const int tid  = threadIdx.x;
    const int b    = blockIdx.x;
    const int w    = tid >> 6;
    const int lane = tid & 63;

    for (int i = tid; i < nwgA; i += 1024) {
        srow[i] = ofs_t[(size_t)b * nwgA + i];
        erow[i] = ofs_t[(size_t)(b + 1) * nwgA + i];
    }
    if (tid < BROWS) hist[tid] = 0;
    __syncthreads();

    if (tid < 256) red[tid] = (tid < nwgA) ? srow[tid] : 0;
    __syncthreads();
    for (int off = 128; off > 0; off >>= 1) {
        if (tid < off) red[tid] += red[tid + off];
        __syncthreads();
    }
    if (tid == 0) s_bbase = red[0];
    __syncthreads();

    // pass 1: in-bucket row histogram
    for (int wg = w; wg < nwgA; wg += 16) {
        const int s = srow[wg];
        const int e = erow[wg];
        const uint2* run = slices + (size_t)wg * TILE;
        for (int i = s + lane; i < e; i += 64)
            atomicAdd(&hist[run[i].x & (BROWS - 1)], 1);
    }
    __syncthreads();

    int v0 = 0;
    if (tid < BROWS) { v0 = hist[tid]; ps[tid] = v0; }
    __syncthreads();
    for (int off = 1; off < BROWS; off <<= 1) {
        int t = 0;
        if (tid < BROWS && tid >= off) t = ps[tid - off];
        __syncthreads();
        if (tid < BROWS) ps[tid] += t;
        __syncthreads();
    }
    if (tid < BROWS) {
        const int excl = s_bbase + ps[tid] - v0;
        curs[tid] = excl;                       // row start
        const int r = (b << BSHIFT) + tid;
        if (r < n) rowptr[r] = excl + v0;       // row end
    }
    __syncthreads();

    // pass 2: scatter into final CSR positions (bucket-private window)
    for (int wg = w; wg < nwgA; wg += 16) {
        const int s = srow[wg];
        const int e = erow[wg];
        const uint2* run = slices + (size_t)wg * TILE;
        for (int i = s + lane; i < e; i += 64) {
            uint2 r = run[i];
            int pos = atomicAdd(&curs[r.x & (BROWS - 1)], 1);
            csr[pos] = ((ull)r.y << 32) | (r.x >> BSHIFT);
        }
    }
}

// ---------------------------------------------------------------------------
// CSR SpMM + fused column stats — round-11: quarter-wave gather.
//
// Round-3 post-mortem: pair-gather (2 edges/instr) gave 104->94us; the gain
// tracked VMEM-instruction halving, not in-flight bytes => model: the gather
// path is limited by request/issue rate, not exposed latency. So halve the
// instruction count again: quarter-wave (16 lanes) per edge, uint4 per lane
// (8 channels). One gather instr covers FOUR edges; csr broadcasts halve too.
// Same cache-line count per edge. Stats via per-quad LDS atomics to keep
// VGPR <= 64 (8 waves/SIMD) -- round-1 showed the occupancy cliff is fatal.
// ---------------------------------------------------------------------------
__global__ __launch_bounds__(256) void spmm_stats_kernel(
    const unsigned* __restrict__ yb,
    const int* __restrict__ rowptr,   // end-form
    const ull* __restrict__ csr,
    float* __restrict__ h,
    float* __restrict__ stats,        // [0..127]=sum, [128..255]=sumsq, zeroed
    int n)
{
    __shared__ int   rp[65];
    __shared__ float ssum[128];
    __shared__ float ssq[128];

    const int tid       = threadIdx.x;
    const int blockRow0 = blockIdx.x * 64;
    const int wv        = tid >> 6;
    const int lane      = tid & 63;
    const int qw        = lane >> 4;     // quarter-wave: which row of the quad
    const int li4       = lane & 15;     // owns channels 8*li4 .. 8*li4+7
    const int rbase     = blockRow0 + wv * 16;

    if (tid < 128) { ssum[tid] = 0.f; ssq[tid] = 0.f; }
    if (tid < 65) {
        int idx = blockRow0 + tid - 1;          // row whose END we need
        rp[tid] = (idx < 0) ? 0 : rowptr[min(idx, n - 1)];
    }
    __syncthreads();

    if (rbase < n) {
        for (int q = 0; q < 4; ++q) {
            const int  r     = rbase + 4 * q + qw;    // this quarter's row
            const bool rowOK = r < n;
            const int  s_    = rowOK ? rp[r - blockRow0]     : 0;
            const int  e_    = rowOK ? rp[r - blockRow0 + 1] : 0;
            const int  nA    = e_ - s_;
            int m = max(nA, __shfl_xor(nA, 16));
            m = max(m, __shfl_xor(m, 32));

            float a0 = 0.f, a1 = 0.f, a2 = 0.f, a3 = 0.f;
            float a4 = 0.f, a5 = 0.f, a6 = 0.f, a7 = 0.f;

            for (int i = 0; i < m; i += 4) {
                // csr chunk (uniform per quarter-wave; clamped, v=0 on dead)
                int i0 = s_ + i;
                ull c0 = csr[(i0 + 0 < e_) ? i0 + 0 : (nA ? e_ - 1 : 0)];
                ull c1 = csr[(i0 + 1 < e_) ? i0 + 1 : (nA ? e_ - 1 : 0)];
                ull c2 = csr[(i0 + 2 < e_) ? i0 + 2 : (nA ? e_ - 1 : 0)];
                ull c3 = csr[(i0 + 3 < e_) ? i0 + 3 : (nA ? e_ - 1 : 0)];

                uint4 u0 = *(const uint4*)(yb + (size_t)(unsigned)c0 * 64 + 4 * li4);
                uint4 u1 = *(const uint4*)(yb + (size_t)(unsigned)c1 * 64 + 4 * li4);
                uint4 u2 = *(const uint4*)(yb + (size_t)(unsigned)c2 * 64 + 4 * li4);
                uint4 u3 = *(const uint4*)(yb + (size_t)(unsigned)c3 * 64 + 4 * li4);

                float v0 = (i0 + 0 < e_) ? __uint_as_float((unsigned)(c0 >> 32)) : 0.f;
                float v1 = (i0 + 1 < e_) ? __uint_as_float((unsigned)(c1 >> 32)) : 0.f;
                float v2 = (i0 + 2 < e_) ? __uint_as_float((unsigned)(c2 >> 32)) : 0.f;
                float v3 = (i0 + 3 < e_) ? __uint_as_float((unsigned)(c3 >> 32)) : 0.f;

                a0 += v0 * bf_lo(u0.x) + v1 * bf_lo(u1.x) + v2 * bf_lo(u2.x) + v3 * bf_lo(u3.x);
                a1 += v0 * bf_hi(u0.x) + v1 * bf_hi(u1.x) + v2 * bf_hi(u2.x) + v3 * bf_hi(u3.x);
                a2 += v0 * bf_lo(u0.y) + v1 * bf_lo(u1.y) + v2 * bf_lo(u2.y) + v3 * bf_lo(u3.y);
                a3 += v0 * bf_hi(u0.y) + v1 * bf_hi(u1.y) + v2 * bf_hi(u2.y) + v3 * bf_hi(u3.y);
                a4 += v0 * bf_lo(u0.z) + v1 * bf_lo(u1.z) + v2 * bf_lo(u2.z) + v3 * bf_lo(u3.z);
                a5 += v0 * bf_hi(u0.z) + v1 * bf_hi(u1.z) + v2 * bf_hi(u2.z) + v3 * bf_hi(u3.z);
                a6 += v0 * bf_lo(u0.w) + v1 * bf_lo(u1.w) + v2 * bf_lo(u2.w) + v3 * bf_lo(u3.w);
                a7 += v0 * bf_hi(u0.w) + v1 * bf_hi(u1.w) + v2 * bf_hi(u2.w) + v3 * bf_hi(u3.w);
            }

            if (rowOK) {
                *(float4*)&h[(size_t)r * D + 8 * li4]     = make_float4(a0, a1, a2, a3);
                *(float4*)&h[(size_t)r * D + 8 * li4 + 4] = make_float4(a4, a5, a6, a7);
                atomicAdd(&ssum[8 * li4 + 0], a0); atomicAdd(&ssum[8 * li4 + 1], a1);
                atomicAdd(&ssum[8 * li4 + 2], a2); atomicAdd(&ssum[8 * li4 + 3], a3);
                atomicAdd(&ssum[8 * li4 + 4], a4); atomicAdd(&ssum[8 * li4 + 5], a5);
                atomicAdd(&ssum[8 * li4 + 6], a6); atomicAdd(&ssum[8 * li4 + 7], a7);
                atomicAdd(&ssq[8 * li4 + 0], a0 * a0); atomicAdd(&ssq[8 * li4 + 1], a1 * a1);
                atomicAdd(&ssq[8 * li4 + 2], a2 * a2); atomicAdd(&ssq[8 * li4 + 3], a3 * a3);
                atomicAdd(&ssq[8 * li4 + 4], a4 * a4); atomicAdd(&ssq[8 * li4 + 5], a5 * a5);
                atomicAdd(&ssq[8 * li4 + 6], a6 * a6); atomicAdd(&ssq[8 * li4 + 7], a7 * a7);
            }
        }
    }
    __syncthreads();
    if (tid < 128) {
        atomicAdd(&stats[tid],       ssum[tid]);
        atomicAdd(&stats[128 + tid], ssq[tid]);
    }
}

// ---------------------------------------------------------------------------
// In-place BatchNorm apply. Linear bias cancels under BN -> omitted.
// ---------------------------------------------------------------------------
__global__ __launch_bounds__(256) void bn_apply_kernel(
    float* __restrict__ h,
    const float* __restrict__ stats,
    const float* __restrict__ gamma,
    const float* __restrict__ beta,
    int n)
{
    __shared__ float s_scale[128];
    __shared__ float s_shift[128];
    const int tid = threadIdx.x;
    if (tid < 128) {
        const float invn = 1.0f / (float)n;
        const float mean = stats[tid] * invn;
        const float var  = stats[128 + tid] * invn - mean * mean;
        const float inv  = rsqrtf(var + BN_EPS);
        const float g    = gamma[tid] * inv;
        s_scale[tid] = g;
        s_shift[tid] = beta[tid] - mean * g;
    }
    __syncthreads();

    float4* h4 = (float4*)h;
    const size_t total = (size_t)n * D / 4;
    const size_t stride = (size_t)gridDim.x * blockDim.x;
    for (size_t i = (size_t)blockIdx.x * blockDim.x + tid; i < total; i += stride) {
        float4 v = h4[i];
        const int c = (int)((i * 4) & (D - 1));
        v.x = v.x * s_scale[c]     + s_shift[c];
        v.y = v.y * s_scale[c + 1] + s_shift[c + 1];
        v.z = v.z * s_scale[c + 2] + s_shift[c + 2];
        v.w = v.w * s_scale[c + 3] + s_shift[c + 3];
        h4[i] = v;
    }
}

// ---------------------------------------------------------------------------
// Fallback (ws too small / shape mismatch): atomic SpMM + GEMM w/ stats.
// ---------------------------------------------------------------------------
__global__ __launch_bounds__(256) void spmm_atomic_kernel(
    const float* __restrict__ x,
    const int* __restrict__ esrc, const int* __restrict__ edst,
    const float* __restrict__ eval, float* __restrict__ agg, int E)
{
    int wave  = (blockIdx.x * blockDim.x + threadIdx.x) >> 6;
    int lane  = threadIdx.x & 63;
    int nwave = (gridDim.x * blockDim.x) >> 6;
    for (int e = wave; e < E; e += nwave) {
        int   s = esrc[e];
        int   d = edst[e];
        float v = eval[e];
        const float2 xv = ((const float2*)(x + (size_t)s * D))[lane];
        float* ar = agg + (size_t)d * D + lane * 2;
        atomicAdd(ar,     xv.x * v);
        atomicAdd(ar + 1, xv.y * v);
    }
}

__global__ __launch_bounds__(256) void gemm_stats_kernel(
    const float* __restrict__ A,
    const float* __restrict__ W,
    float* __restrict__ h,
    float* __restrict__ stats,
    int n)
{
    __shared__ float sW[128 * 128];
    __shared__ float sA[32][128];
    const int tid = threadIdx.x;
    const float4* W4  = (const float4*)W;
    float4*       sW4 = (float4*)sW;
#pragma unroll
    for (int i = 0; i < 16; i++) sW4[tid + 256 * i] = W4[tid + 256 * i];
    const int row0 = blockIdx.x * 32;
    const float4* A4  = (const float4*)(A + (size_t)row0 * D);
    float4*       sA4 = (float4*)&sA[0][0];
#pragma unroll
    for (int i = 0; i < 4; i++) {
        int idx = tid + 256 * i;
        sA4[idx] = ((size_t)row0 * D + (size_t)idx * 4 < (size_t)n * D)
                       ? A4[idx] : make_float4(0.f, 0.f, 0.f, 0.f);
    }
    __syncthreads();
    const int tx = tid & 31, ty = tid >> 5, c0 = tx * 4;
    float acc[4][4] = {};
    for (int k = 0; k < 128; k++) {
        const float4 w = *(const float4*)&sW[k * 128 + c0];
#pragma unroll
        for (int j = 0; j < 4; j++) {
            const float a = sA[ty + 8 * j][k];
            acc[j][0] += a * w.x; acc[j][1] += a * w.y;
            acc[j][2] += a * w.z; acc[j][3] += a * w.w;
        }
    }
#pragma unroll
    for (int j = 0; j < 4; j++) {
        const int row = row0 + ty + 8 * j;
        if (row < n)
            *(float4*)&h[(size_t)row * D + c0] =
                make_float4(acc[j][0], acc[j][1], acc[j][2], acc[j][3]);
    }
    __syncthreads();
    float* csum = &sA[0][0];
    float* csq  = csum + 128;
    if (tid < 128) { csum[tid] = 0.f; csq[tid] = 0.f; }
    __syncthreads();
#pragma unroll
    for (int c = 0; c < 4; c++) {
        float s = 0.f, q = 0.f;
#pragma unroll
        for (int j = 0; j < 4; j++) { s += acc[j][c]; q += acc[j][c] * acc[j][c]; }
        atomicAdd(&csum[c0 + c], s);
        atomicAdd(&csq[c0 + c], q);
    }
    __syncthreads();
    if (tid < 128) {
        atomicAdd(&stats[tid],       csum[tid]);
        atomicAdd(&stats[128 + tid], csq[tid]);
    }
}

// ---------------------------------------------------------------------------
extern "C" void kernel_launch(void* const* d_in, const int* in_sizes, int n_in,
                              void* d_out, int out_size, void* d_ws, size_t ws_size,
                              hipStream_t stream)
{
    const float* x     = (const float*)d_in[0];
    const int*   esrc  = (const int*)d_in[1];
    const int*   edst  = (const int*)d_in[2];
    const float* evals = (const float*)d_in[3];
    const float* W     = (const float*)d_in[4];
    // d_in[5] = bias: unused — cancels exactly under BatchNorm.
    const float* gamma = (const float*)d_in[6];
    const float* beta  = (const float*)d_in[7];
    float* out = (float*)d_out;

    const int n = in_sizes[0] / D;   // 100000
    const int E = in_sizes[1];       // 1600000

    const int B     = (n + BROWS - 1) >> BSHIFT;   // 196 buckets
    const int nwgA  = (E + TILE - 1) / TILE;       // 196 tiles
    const int ngemm = (n + 31) / 32;               // 3125 gemm blocks

    // Workspace (word-indexed):
    //   yb      [n*64]            25.6 MB (packed bf16 y = x@W)
    //   stats   [256]             zeroed (1KB memset)
    //   ofs_t   [(B+1)*nwgA]      ~155 KB (transposed: [bucket][wg])
    //   rowptr  [n]
    //   (pad to even word)
    //   slices  uint2[nwgA*TILE]  12.85 MB
    //   csr     ull  [E]          12.8 MB
    unsigned* yb     = (unsigned*)d_ws;
    float*    stats  = (float*)(yb + (size_t)n * 64);
    int*      ofs_t  = (int*)(stats + 256);
    int*      rowptr = ofs_t + (size_t)(B + 1) * nwgA;
    size_t    w_off  = (size_t)n * 64 + 256 + (size_t)(B + 1) * nwgA + n;
    w_off += (w_off & 1);                          // 8B alignment
    uint2*    slices = (uint2*)((unsigned*)d_ws + w_off);
    ull*      csr    = (ull*)(slices + (size_t)nwgA * TILE);
    const size_t need = (w_off + (size_t)nwgA * TILE * 2 + (size_t)E * 2) * 4;

    if (ws_size >= need && B <= 256 && nwgA <= 256) {
        hipMemsetAsync(stats, 0, 256 * 4, stream);
        phase1_kernel<<<nwgA + ngemm, 256, 0, stream>>>(
            x, W, yb, n, esrc, edst, evals, slices, ofs_t, B, nwgA, E);
        binB_kernel<<<B, 1024, 0, stream>>>(
            slices, ofs_t, rowptr, csr, B, nwgA, n);
        spmm_stats_kernel<<<(n + 63) / 64, 256, 0, stream>>>(
            yb, rowptr, csr, out, stats, n);
        bn_apply_kernel<<<2048, 256, 0, stream>>>(out, stats, gamma, beta, n);
    } else {
        // fallback: fp32 atomic-scatter path
        float* agg = (float*)d_ws;
        float* st  = agg + (size_t)n * D;
        hipMemsetAsync(d_ws, 0, ((size_t)n * D + 256) * 4, stream);
        spmm_atomic_kernel<<<4096, 256, 0, stream>>>(x, esrc, edst, evals, agg, E);
        gemm_stats_kernel<<<(n + 31) / 32, 256, 0, stream>>>(agg, W, out, st, n);
        bn_apply_kernel<<<2048, 256, 0, stream>>>(out, st, gamma, beta, n);
    }
}

// Round 5
// 339.099 us; speedup vs baseline: 1.1275x; 1.1275x over previous
//
#include <hip/hip_runtime.h>
#include <math.h>

// Problem constants: N=100000, E=1600000, D_IN=D_OUT=128
#define D 128
#define BSHIFT 9              // 512 dst rows per bucket
#define BROWS 512
#define TILE 8192             // edges per binA workgroup
constexpr float BN_EPS = 1e-5f;
typedef unsigned long long ull;

// bf16 helpers (manual, RNE) ------------------------------------------------
__device__ __forceinline__ unsigned f2bf_rne(float f) {
    unsigned u = __float_as_uint(f);
    return (u + 0x7FFFu + ((u >> 16) & 1u)) >> 16;
}
__device__ __forceinline__ float bf_lo(unsigned u) { return __uint_as_float(u << 16); }
__device__ __forceinline__ float bf_hi(unsigned u) { return __uint_as_float(u & 0xFFFF0000u); }

// ---------------------------------------------------------------------------
// phase1: fused dispatch. Blocks [0,nwgA) run binA (bucket sort pass A);
// blocks [nwgA, nwgA+ngemm) run gemm_pack (y = x@W, packed to bf16).
// W read directly from global (L2-broadcast); LDS 16KB -> 8 blocks/CU.
// Round-5 change: binA also counts edges per dst row into global rowcnt
// (zeroed beforehand) so binB can skip its histogram pass entirely. The
// extra global atomic rides the existing scatter loop and overlaps the gemm.
// ---------------------------------------------------------------------------
__global__ __launch_bounds__(256) void phase1_kernel(
    const float* __restrict__ A,
    const float* __restrict__ W,
    unsigned* __restrict__ yb,
    int n,
    const int* __restrict__ esrc, const int* __restrict__ edst,
    const float* __restrict__ evals,
    uint2* __restrict__ slices,        // [nwgA * TILE]
    int* __restrict__ ofs_t,           // [(B+1) * nwgA], transposed [bucket][wg]
    int* __restrict__ rowcnt,          // [n], zeroed; edges per dst row
    int B, int nwgA, int E)
{
    __shared__ __align__(16) char smem[16384];
    const int tid = threadIdx.x;

    if ((int)blockIdx.x < nwgA) {
        // ------------------- binA: coarse bucket sort -------------------
        int* h   = (int*)smem;
        int* ps  = h + 256;
        int* cur = ps + 256;
        const int wg = blockIdx.x;
        const int e0 = wg * TILE;
        const int e1 = min(e0 + TILE, E);

        h[tid] = 0;
        __syncthreads();
        for (int e = e0 + tid; e < e1; e += 256)
            atomicAdd(&h[edst[e] >> BSHIFT], 1);
        __syncthreads();

        const int v = h[tid];
        ps[tid] = v;
        __syncthreads();
        for (int off = 1; off < 256; off <<= 1) {
            int t = (tid >= off) ? ps[tid - off] : 0;
            __syncthreads();
            if (tid >= off) ps[tid] += t;
            __syncthreads();
        }
        const int excl = ps[tid] - v;
        if (tid < B) {
            cur[tid] = excl;
            ofs_t[(size_t)tid * nwgA + wg] = excl;
        }
        if (tid == 0) ofs_t[(size_t)B * nwgA + wg] = e1 - e0;  // sentinel
        __syncthreads();

        uint2* slice = slices + (size_t)wg * TILE;
        for (int e = e0 + tid; e < e1; e += 256) {
            int d = edst[e];
            int b = d >> BSHIFT;
            int p = atomicAdd(&cur[b], 1);
            atomicAdd(&rowcnt[d], 1);          // per-row count for binB
            uint2 rec;
            rec.x = (unsigned)(d & (BROWS - 1)) | ((unsigned)esrc[e] << BSHIFT);
            rec.y = __float_as_uint(evals[e]);
            slice[p] = rec;
        }
    } else {
        // ------------------- gemm_pack: y = x@W -> bf16 -------------------
        float (*sA)[128] = (float(*)[128])smem;            // 16 KB

        const int row0 = (blockIdx.x - nwgA) * 32;
        const float4* A4  = (const float4*)(A + (size_t)row0 * D);
        float4*       sA4 = (float4*)&sA[0][0];
#pragma unroll
        for (int i = 0; i < 4; i++) {
            int idx = tid + 256 * i;
            sA4[idx] = ((size_t)row0 * D + (size_t)idx * 4 < (size_t)n * D)
                           ? A4[idx] : make_float4(0.f, 0.f, 0.f, 0.f);
        }
        __syncthreads();

        const int tx = tid & 31;
        const int ty = tid >> 5;
        const float4* W4 = (const float4*)W;   // global, L2-broadcast

        float acc[4][4] = {};
        for (int k0 = 0; k0 < 128; k0 += 4) {
            float4 a[4];
#pragma unroll
            for (int j = 0; j < 4; j++)
                a[j] = *(const float4*)&sA[ty + 8 * j][k0];
#pragma unroll
            for (int kk = 0; kk < 4; kk++) {
                const float4 w = W4[(k0 + kk) * 32 + tx];
                const float ak[4] = { kk == 0 ? a[0].x : kk == 1 ? a[0].y : kk == 2 ? a[0].z : a[0].w,
                                      kk == 0 ? a[1].x : kk == 1 ? a[1].y : kk == 2 ? a[1].z : a[1].w,
                                      kk == 0 ? a[2].x : kk == 1 ? a[2].y : kk == 2 ? a[2].z : a[2].w,
                                      kk == 0 ? a[3].x : kk == 1 ? a[3].y : kk == 2 ? a[3].z : a[3].w };
#pragma unroll
                for (int j = 0; j < 4; j++) {
                    acc[j][0] += ak[j] * w.x;
                    acc[j][1] += ak[j] * w.y;
                    acc[j][2] += ak[j] * w.z;
                    acc[j][3] += ak[j] * w.w;
                }
            }
        }

#pragma unroll
        for (int j = 0; j < 4; j++) {
            const int row = row0 + ty + 8 * j;
            if (row < n) {
                uint2 o;
                o.x = f2bf_rne(acc[j][0]) | (f2bf_rne(acc[j][1]) << 16);
                o.y = f2bf_rne(acc[j][2]) | (f2bf_rne(acc[j][3]) << 16);
                ((uint2*)(yb + (size_t)row * 64))[tx] = o;
            }
        }
    }
}

// ---------------------------------------------------------------------------
// binB: one 1024-thread wg (16 waves) per bucket.
// Round-5: histogram comes from rowcnt (built by binA) -> the old pass 1
// (full 12.85MB re-read + 1.6M LDS atomics) is gone. binB = stage bounds,
// scan, scatter.
// ---------------------------------------------------------------------------
__global__ __launch_bounds__(1024) void binB_kernel(
    const uint2* __restrict__ slices,
    const int* __restrict__ ofs_t,
    const int* __restrict__ rowcnt,    // [n]
    int* __restrict__ rowptr,          // [n], end-form
    ull* __restrict__ csr,             // [E]
    int B, int nwgA, int n)
{
    __shared__ int srow[256];
    __shared__ int erow[256];
    __shared__ int red[256];
    __shared__ int curs[BROWS];
    __shared__ int ps[BROWS];
    __shared__ int s_bbase;

    const int tid  = threadIdx.x;
    const int b    = blockIdx.x;
    const int w    = tid >> 6;
    const int lane = tid & 63;

    // stage run bounds (coalesced: two contiguous rows of nwgA ints)
    for (int i = tid; i < nwgA; i += 1024) {
        srow[i] = ofs_t[(size_t)b * nwgA + i];
        erow[i] = ofs_t[(size_t)(b + 1) * nwgA + i];
    }
    __syncthreads();

    // bucket base = sum(srow[0..nwgA))
    if (tid < 256) red[tid] = (tid < nwgA) ? srow[tid] : 0;
    __syncthreads();
    for (int off = 128; off > 0; off >>= 1) {
        if (tid < off) red[tid] += red[tid + off];
        __syncthreads();
    }
    if (tid == 0) s_bbase = red[0];
    __syncthreads();

    // per-row counts from rowcnt (built by binA)
    int v0 = 0;
    if (tid < BROWS) {
        const int r = (b << BSHIFT) + tid;
        v0 = (r < n) ? rowcnt[r] : 0;
        ps[tid] = v0;
    }
    __syncthreads();
    for (int off = 1; off < BROWS; off <<= 1) {
        int t = 0;
        if (tid < BROWS && tid >= off) t = ps[tid - off];
        __syncthreads();
        if (tid < BROWS) ps[tid] += t;
        __syncthreads();
    }
    if (tid < BROWS) {
        const int excl = s_bbase + ps[tid] - v0;
        curs[tid] = excl;                       // row start
        const int r = (b << BSHIFT) + tid;
        if (r < n) rowptr[r] = excl + v0;       // row end
    }
    __syncthreads();

    // scatter into final CSR positions (bucket-private window)
    for (int wg = w; wg < nwgA; wg += 16) {
        const int s = srow[wg];
        const int e = erow[wg];
        const uint2* run = slices + (size_t)wg * TILE;
        for (int i = s + lane; i < e; i += 64) {
            uint2 r = run[i];
            int pos = atomicAdd(&curs[r.x & (BROWS - 1)], 1);
            csr[pos] = ((ull)r.y << 32) | (r.x >> BSHIFT);
        }
    }
}

// ---------------------------------------------------------------------------
// CSR SpMM + fused column stats — round-3 pair-gather version (94us verified).
// Round-4's quarter-wave widening REGRESSED 94->170 despite fewer VMEM
// instructions -> this loop shape is the empirical local optimum; frozen.
// ---------------------------------------------------------------------------
__global__ __launch_bounds__(256) void spmm_stats_kernel(
    const unsigned* __restrict__ yb,
    const int* __restrict__ rowptr,   // end-form
    const ull* __restrict__ csr,
    float* __restrict__ h,
    float* __restrict__ stats,        // [0..127]=sum, [128..255]=sumsq, zeroed
    int n)
{
    __shared__ int   rp[65];
    __shared__ float ssum[128];
    __shared__ float ssq[128];

    const int tid       = threadIdx.x;
    const int blockRow0 = blockIdx.x * 64;
    const int wv        = tid >> 6;
    const int lane      = tid & 63;
    const int half      = lane >> 5;     // which row of the pair
    const int li        = lane & 31;     // owns channels 4*li .. 4*li+3
    const int rbase     = blockRow0 + wv * 16;

    if (tid < 128) { ssum[tid] = 0.f; ssq[tid] = 0.f; }
    if (tid < 65) {
        int idx = blockRow0 + tid - 1;          // row whose END we need
        rp[tid] = (idx < 0) ? 0 : rowptr[min(idx, n - 1)];
    }
    __syncthreads();

    float s0 = 0.f, s1 = 0.f, s2 = 0.f, s3 = 0.f;
    float q0 = 0.f, q1 = 0.f, q2 = 0.f, q3 = 0.f;

    if (rbase < n) {
        for (int pr = 0; pr < 16; pr += 2) {
            const int  rA    = rbase + pr + half;     // this half's row
            const bool rowOK = rA < n;
            const int  s_    = rowOK ? rp[rA - blockRow0]     : 0;
            const int  e_    = rowOK ? rp[rA - blockRow0 + 1] : 0;
            const int  nA    = e_ - s_;
            // trip count: max of the two halves' row lengths
            const int  nMax  = max(nA, __shfl_xor(nA, 32));

            float a0 = 0.f, a1 = 0.f, a2 = 0.f, a3 = 0.f;
            for (int i = 0; i < nMax; i += 8) {
                ull cd[8];
#pragma unroll
                for (int j = 0; j < 8; j++) {
                    int idx = s_ + i + j;
                    int ce  = (idx < e_) ? idx : (nA ? e_ - 1 : 0);
                    cd[j] = csr[ce];
                }
                uint2 u[8];
                float v[8];
#pragma unroll
                for (int j = 0; j < 8; j++) {
                    u[j] = *(const uint2*)(yb + (size_t)(unsigned)cd[j] * 64 + 2 * li);
                    v[j] = (s_ + i + j < e_)
                               ? __uint_as_float((unsigned)(cd[j] >> 32))
                               : 0.f;
                }
#pragma unroll
                for (int j = 0; j < 8; j++) {
                    a0 += v[j] * bf_lo(u[j].x);
                    a1 += v[j] * bf_hi(u[j].x);
                    a2 += v[j] * bf_lo(u[j].y);
                    a3 += v[j] * bf_hi(u[j].y);
                }
            }

            if (rowOK) {
                *(float4*)&h[(size_t)rA * D + 4 * li] = make_float4(a0, a1, a2, a3);
                s0 += a0; s1 += a1; s2 += a2; s3 += a3;
                q0 += a0 * a0; q1 += a1 * a1; q2 += a2 * a2; q3 += a3 * a3;
            }
        }

        atomicAdd(&ssum[4 * li + 0], s0); atomicAdd(&ssum[4 * li + 1], s1);
        atomicAdd(&ssum[4 * li + 2], s2); atomicAdd(&ssum[4 * li + 3], s3);
        atomicAdd(&ssq [4 * li + 0], q0); atomicAdd(&ssq [4 * li + 1], q1);
        atomicAdd(&ssq [4 * li + 2], q2); atomicAdd(&ssq [4 * li + 3], q3);
    }
    __syncthreads();
    if (tid < 128) {
        atomicAdd(&stats[tid],       ssum[tid]);
        atomicAdd(&stats[128 + tid], ssq[tid]);
    }
}

// ---------------------------------------------------------------------------
// In-place BatchNorm apply. Linear bias cancels under BN -> omitted.
// ---------------------------------------------------------------------------
__global__ __launch_bounds__(256) void bn_apply_kernel(
    float* __restrict__ h,
    const float* __restrict__ stats,
    const float* __restrict__ gamma,
    const float* __restrict__ beta,
    int n)
{
    __shared__ float s_scale[128];
    __shared__ float s_shift[128];
    const int tid = threadIdx.x;
    if (tid < 128) {
        const float invn = 1.0f / (float)n;
        const float mean = stats[tid] * invn;
        const float var  = stats[128 + tid] * invn - mean * mean;
        const float inv  = rsqrtf(var + BN_EPS);
        const float g    = gamma[tid] * inv;
        s_scale[tid] = g;
        s_shift[tid] = beta[tid] - mean * g;
    }
    __syncthreads();

    float4* h4 = (float4*)h;
    const size_t total = (size_t)n * D / 4;
    const size_t stride = (size_t)gridDim.x * blockDim.x;
    for (size_t i = (size_t)blockIdx.x * blockDim.x + tid; i < total; i += stride) {
        float4 v = h4[i];
        const int c = (int)((i * 4) & (D - 1));
        v.x = v.x * s_scale[c]     + s_shift[c];
        v.y = v.y * s_scale[c + 1] + s_shift[c + 1];
        v.z = v.z * s_scale[c + 2] + s_shift[c + 2];
        v.w = v.w * s_scale[c + 3] + s_shift[c + 3];
        h4[i] = v;
    }
}

// ---------------------------------------------------------------------------
// Fallback (ws too small / shape mismatch): atomic SpMM + GEMM w/ stats.
// ---------------------------------------------------------------------------
__global__ __launch_bounds__(256) void spmm_atomic_kernel(
    const float* __restrict__ x,
    const int* __restrict__ esrc, const int* __restrict__ edst,
    const float* __restrict__ eval, float* __restrict__ agg, int E)
{
    int wave  = (blockIdx.x * blockDim.x + threadIdx.x) >> 6;
    int lane  = threadIdx.x & 63;
    int nwave = (gridDim.x * blockDim.x) >> 6;
    for (int e = wave; e < E; e += nwave) {
        int   s = esrc[e];
        int   d = edst[e];
        float v = eval[e];
        const float2 xv = ((const float2*)(x + (size_t)s * D))[lane];
        float* ar = agg + (size_t)d * D + lane * 2;
        atomicAdd(ar,     xv.x * v);
        atomicAdd(ar + 1, xv.y * v);
    }
}

__global__ __launch_bounds__(256) void gemm_stats_kernel(
    const float* __restrict__ A,
    const float* __restrict__ W,
    float* __restrict__ h,
    float* __restrict__ stats,
    int n)
{
    __shared__ float sW[128 * 128];
    __shared__ float sA[32][128];
    const int tid = threadIdx.x;
    const float4* W4  = (const float4*)W;
    float4*       sW4 = (float4*)sW;
#pragma unroll
    for (int i = 0; i < 16; i++) sW4[tid + 256 * i] = W4[tid + 256 * i];
    const int row0 = blockIdx.x * 32;
    const float4* A4  = (const float4*)(A + (size_t)row0 * D);
    float4*       sA4 = (float4*)&sA[0][0];
#pragma unroll
    for (int i = 0; i < 4; i++) {
        int idx = tid + 256 * i;
        sA4[idx] = ((size_t)row0 * D + (size_t)idx * 4 < (size_t)n * D)
                       ? A4[idx] : make_float4(0.f, 0.f, 0.f, 0.f);
    }
    __syncthreads();
    const int tx = tid & 31, ty = tid >> 5, c0 = tx * 4;
    float acc[4][4] = {};
    for (int k = 0; k < 128; k++) {
        const float4 w = *(const float4*)&sW[k * 128 + c0];
#pragma unroll
        for (int j = 0; j < 4; j++) {
            const float a = sA[ty + 8 * j][k];
            acc[j][0] += a * w.x; acc[j][1] += a * w.y;
            acc[j][2] += a * w.z; acc[j][3] += a * w.w;
        }
    }
#pragma unroll
    for (int j = 0; j < 4; j++) {
        const int row = row0 + ty + 8 * j;
        if (row < n)
            *(float4*)&h[(size_t)row * D + c0] =
                make_float4(acc[j][0], acc[j][1], acc[j][2], acc[j][3]);
    }
    __syncthreads();
    float* csum = &sA[0][0];
    float* csq  = csum + 128;
    if (tid < 128) { csum[tid] = 0.f; csq[tid] = 0.f; }
    __syncthreads();
#pragma unroll
    for (int c = 0; c < 4; c++) {
        float s = 0.f, q = 0.f;
#pragma unroll
        for (int j = 0; j < 4; j++) { s += acc[j][c]; q += acc[j][c] * acc[j][c]; }
        atomicAdd(&csum[c0 + c], s);
        atomicAdd(&csq[c0 + c], q);
    }
    __syncthreads();
    if (tid < 128) {
        atomicAdd(&stats[tid],       csum[tid]);
        atomicAdd(&stats[128 + tid], csq[tid]);
    }
}

// ---------------------------------------------------------------------------
extern "C" void kernel_launch(void* const* d_in, const int* in_sizes, int n_in,
                              void* d_out, int out_size, void* d_ws, size_t ws_size,
                              hipStream_t stream)
{
    const float* x     = (const float*)d_in[0];
    const int*   esrc  = (const int*)d_in[1];
    const int*   edst  = (const int*)d_in[2];
    const float* evals = (const float*)d_in[3];
    const float* W     = (const float*)d_in[4];
    // d_in[5] = bias: unused — cancels exactly under BatchNorm.
    const float* gamma = (const float*)d_in[6];
    const float* beta  = (const float*)d_in[7];
    float* out = (float*)d_out;

    const int n = in_sizes[0] / D;   // 100000
    const int E = in_sizes[1];       // 1600000

    const int B     = (n + BROWS - 1) >> BSHIFT;   // 196 buckets
    const int nwgA  = (E + TILE - 1) / TILE;       // 196 tiles
    const int ngemm = (n + 31) / 32;               // 3125 gemm blocks

    // Workspace (word-indexed):
    //   yb      [n*64]            25.6 MB (packed bf16 y = x@W)
    //   stats   [256]             zeroed (1KB memset)
    //   ofs_t   [(B+1)*nwgA]      ~155 KB (transposed: [bucket][wg])
    //   rowptr  [n]
    //   rowcnt  [n]               zeroed (400KB memset); per-row edge counts
    //   (pad to even word)
    //   slices  uint2[nwgA*TILE]  12.85 MB
    //   csr     ull  [E]          12.8 MB
    unsigned* yb     = (unsigned*)d_ws;
    float*    stats  = (float*)(yb + (size_t)n * 64);
    int*      ofs_t  = (int*)(stats + 256);
    int*      rowptr = ofs_t + (size_t)(B + 1) * nwgA;
    int*      rowcnt = rowptr + n;
    size_t    w_off  = (size_t)n * 64 + 256 + (size_t)(B + 1) * nwgA + 2 * (size_t)n;
    w_off += (w_off & 1);                          // 8B alignment
    uint2*    slices = (uint2*)((unsigned*)d_ws + w_off);
    ull*      csr    = (ull*)(slices + (size_t)nwgA * TILE);
    const size_t need = (w_off + (size_t)nwgA * TILE * 2 + (size_t)E * 2) * 4;

    if (ws_size >= need && B <= 256 && nwgA <= 256) {
        hipMemsetAsync(stats, 0, 256 * 4, stream);
        hipMemsetAsync(rowcnt, 0, (size_t)n * 4, stream);
        phase1_kernel<<<nwgA + ngemm, 256, 0, stream>>>(
            x, W, yb, n, esrc, edst, evals, slices, ofs_t, rowcnt, B, nwgA, E);
        binB_kernel<<<B, 1024, 0, stream>>>(
            slices, ofs_t, rowcnt, rowptr, csr, B, nwgA, n);
        spmm_stats_kernel<<<(n + 63) / 64, 256, 0, stream>>>(
            yb, rowptr, csr, out, stats, n);
        bn_apply_kernel<<<2048, 256, 0, stream>>>(out, stats, gamma, beta, n);
    } else {
        // fallback: fp32 atomic-scatter path
        float* agg = (float*)d_ws;
        float* st  = agg + (size_t)n * D;
        hipMemsetAsync(d_ws, 0, ((size_t)n * D + 256) * 4, stream);
        spmm_atomic_kernel<<<4096, 256, 0, stream>>>(x, esrc, edst, evals, agg, E);
        gemm_stats_kernel<<<(n + 31) / 32, 256, 0, stream>>>(agg, W, out, st, n);
        bn_apply_kernel<<<2048, 256, 0, stream>>>(out, st, gamma, beta, n);
    }
}

// Round 6
// 291.614 us; speedup vs baseline: 1.3111x; 1.1628x over previous
//
#include <hip/hip_runtime.h>
#include <math.h>

// Problem constants: N=100000, E=1600000, D_IN=D_OUT=128
#define D 128
#define BSHIFT 9              // 512 dst rows per bucket
#define BROWS 512
#define TILE 8192             // edges per binA workgroup
constexpr float BN_EPS = 1e-5f;
typedef unsigned long long ull;
typedef __attribute__((ext_vector_type(8))) short short8v;   // 8 bf16 (4 VGPR)
typedef __attribute__((ext_vector_type(4))) float f32x4;     // MFMA acc

// bf16 helpers (manual, RNE) ------------------------------------------------
__device__ __forceinline__ unsigned f2bf_rne(float f) {
    unsigned u = __float_as_uint(f);
    return (u + 0x7FFFu + ((u >> 16) & 1u)) >> 16;
}
__device__ __forceinline__ float bf_lo(unsigned u) { return __uint_as_float(u << 16); }
__device__ __forceinline__ float bf_hi(unsigned u) { return __uint_as_float(u & 0xFFFF0000u); }
// split f into bf16 hi + bf16 lo (f ~ hi + lo, rel err ~2^-17)
__device__ __forceinline__ void split_bf16(float f, unsigned& hi, unsigned& lo) {
    hi = f2bf_rne(f);
    lo = f2bf_rne(f - bf_lo(hi));
}

// ---------------------------------------------------------------------------
// wprep: W fp32 [K=128][N=128] -> transposed bf16 hi/lo [N][K] so that gemm
// B-fragments (8 consecutive k for fixed n) are contiguous 16B loads.
// ---------------------------------------------------------------------------
__global__ __launch_bounds__(256) void wprep_kernel(
    const float* __restrict__ W,
    unsigned short* __restrict__ whiT,
    unsigned short* __restrict__ wloT)
{
    int idx = blockIdx.x * 256 + threadIdx.x;      // 64 blocks -> 16384
    if (idx < 128 * 128) {
        int k = idx >> 7, nn = idx & 127;
        unsigned hi, lo;
        split_bf16(W[idx], hi, lo);
        whiT[nn * 128 + k] = (unsigned short)hi;
        wloT[nn * 128 + k] = (unsigned short)lo;
    }
}

// ---------------------------------------------------------------------------
// phase1: fused dispatch. Blocks [0,nwgA) run binA (bucket sort pass A);
// blocks [nwgA, nwgA+ngemm) run gemm_pack (y = x@W -> bf16) on MFMA.
//
// Round-6: GEMM moved to matrix cores via split-bf16 (xh+xl)(Wh+Wl), three
// products, fp32 accumulate -> ~fp32 accuracy (err ~2^-17 << bf16 output
// rounding). 64 rows/block, 4 waves, mfma_f32_16x16x32_bf16.
// Round-4/5 phase1 edits (W-from-global fp32 loop, rowcnt atomics) reverted:
// they cost +35us and ballooned WRITE_SIZE to 100MB.
// ---------------------------------------------------------------------------
__global__ __launch_bounds__(256) void phase1_kernel(
    const float* __restrict__ A,
    const unsigned short* __restrict__ whiT,
    const unsigned short* __restrict__ wloT,
    unsigned* __restrict__ yb,
    int n,
    const int* __restrict__ esrc, const int* __restrict__ edst,
    const float* __restrict__ evals,
    uint2* __restrict__ slices,        // [nwgA * TILE]
    int* __restrict__ ofs_t,           // [(B+1) * nwgA], transposed [bucket][wg]
    int B, int nwgA, int E)
{
    // gemm: x_hi[64][136] u16 (17408B) + x_lo (17408B) = 34816B;
    //       C fp32 [64][132] (33792B) aliases after compute.
    // binA: first 3KB as int scratch.
    __shared__ __align__(16) char smem[34816];
    const int tid = threadIdx.x;

    if ((int)blockIdx.x < nwgA) {
        // ------------------- binA: coarse bucket sort -------------------
        int* h   = (int*)smem;
        int* ps  = h + 256;
        int* cur = ps + 256;
        const int wg = blockIdx.x;
        const int e0 = wg * TILE;
        const int e1 = min(e0 + TILE, E);

        h[tid] = 0;
        __syncthreads();
        for (int e = e0 + tid; e < e1; e += 256)
            atomicAdd(&h[edst[e] >> BSHIFT], 1);
        __syncthreads();

        const int v = h[tid];
        ps[tid] = v;
        __syncthreads();
        for (int off = 1; off < 256; off <<= 1) {
            int t = (tid >= off) ? ps[tid - off] : 0;
            __syncthreads();
            if (tid >= off) ps[tid] += t;
            __syncthreads();
        }
        const int excl = ps[tid] - v;
        if (tid < B) {
            cur[tid] = excl;
            ofs_t[(size_t)tid * nwgA + wg] = excl;
        }
        if (tid == 0) ofs_t[(size_t)B * nwgA + wg] = e1 - e0;  // sentinel
        __syncthreads();

        uint2* slice = slices + (size_t)wg * TILE;
        for (int e = e0 + tid; e < e1; e += 256) {
            int d = edst[e];
            int b = d >> BSHIFT;
            int p = atomicAdd(&cur[b], 1);
            uint2 rec;
            rec.x = (unsigned)(d & (BROWS - 1)) | ((unsigned)esrc[e] << BSHIFT);
            rec.y = __float_as_uint(evals[e]);
            slice[p] = rec;
        }
    } else {
        // ------------- gemm_pack (MFMA): y = x@W -> bf16 -------------
        unsigned short* xh = (unsigned short*)smem;          // [64][136]
        unsigned short* xl = xh + 64 * 136;

        const int row0 = ((int)blockIdx.x - nwgA) * 64;
        const float4* A4 = (const float4*)(A + (size_t)row0 * D);

        // stage + split x tile: 2048 float4s, 8 per thread
#pragma unroll
        for (int i = 0; i < 8; i++) {
            const int idx = tid + 256 * i;
            const int row = idx >> 5, c4 = idx & 31;
            float4 v = (row0 + row < n) ? A4[idx]
                                        : make_float4(0.f, 0.f, 0.f, 0.f);
            unsigned h0, h1, h2, h3, l0, l1, l2, l3;
            split_bf16(v.x, h0, l0); split_bf16(v.y, h1, l1);
            split_bf16(v.z, h2, l2); split_bf16(v.w, h3, l3);
            unsigned short* ph = xh + (size_t)row * 136 + c4 * 4;
            unsigned short* pl = xl + (size_t)row * 136 + c4 * 4;
            *(uint2*)ph = make_uint2(h0 | (h1 << 16), h2 | (h3 << 16));
            *(uint2*)pl = make_uint2(l0 | (l1 << 16), l2 | (l3 << 16));
        }
        __syncthreads();

        const int wv = tid >> 6;         // wave -> cols [32wv, 32wv+32)
        const int l  = tid & 63;
        const int lr = l & 15;           // A row / B col within 16-tile
        const int lg = l >> 4;           // k-group (8 bf16 each)
        const int colbase = wv * 32;

        f32x4 acc[4][2];
#pragma unroll
        for (int rt = 0; rt < 4; rt++)
#pragma unroll
            for (int ct = 0; ct < 2; ct++)
                acc[rt][ct] = (f32x4){0.f, 0.f, 0.f, 0.f};

        for (int k0 = 0; k0 < 128; k0 += 32) {
            const int kf = k0 + lg * 8;
            short8v ah[4], al[4];
#pragma unroll
            for (int rt = 0; rt < 4; rt++) {
                const unsigned short* p = xh + (size_t)(16 * rt + lr) * 136 + kf;
                const unsigned short* q = xl + (size_t)(16 * rt + lr) * 136 + kf;
                ah[rt] = *(const short8v*)p;
                al[rt] = *(const short8v*)q;
            }
            short8v bh[2], bl[2];
#pragma unroll
            for (int ct = 0; ct < 2; ct++) {
                const int nidx = colbase + 16 * ct + lr;
                bh[ct] = *(const short8v*)(whiT + (size_t)nidx * 128 + kf);
                bl[ct] = *(const short8v*)(wloT + (size_t)nidx * 128 + kf);
            }
#pragma unroll
            for (int rt = 0; rt < 4; rt++)
#pragma unroll
                for (int ct = 0; ct < 2; ct++) {
                    acc[rt][ct] = __builtin_amdgcn_mfma_f32_16x16x32_bf16(
                        ah[rt], bh[ct], acc[rt][ct], 0, 0, 0);
                    acc[rt][ct] = __builtin_amdgcn_mfma_f32_16x16x32_bf16(
                        ah[rt], bl[ct], acc[rt][ct], 0, 0, 0);
                    acc[rt][ct] = __builtin_amdgcn_mfma_f32_16x16x32_bf16(
                        al[rt], bh[ct], acc[rt][ct], 0, 0, 0);
                }
        }
        __syncthreads();                 // all waves done reading xh/xl

        // C/D layout (verified, guide S3): col = lane&15, row = (lane>>4)*4+r
        float* Cl = (float*)smem;        // [64][132]
#pragma unroll
        for (int rt = 0; rt < 4; rt++)
#pragma unroll
            for (int ct = 0; ct < 2; ct++)
#pragma unroll
                for (int r = 0; r < 4; r++) {
                    const int row = 16 * rt + lg * 4 + r;
                    const int col = colbase + 16 * ct + lr;
                    Cl[row * 132 + col] = acc[rt][ct][r];
                }
        __syncthreads();

        // pack fp32 -> bf16 pairs and store (2048 uint2, 8 per thread)
#pragma unroll
        for (int i = 0; i < 8; i++) {
            const int idx = tid + 256 * i;
            const int row = idx >> 5, p = idx & 31;
            const float* c4 = Cl + row * 132 + p * 4;
            uint2 o;
            o.x = f2bf_rne(c4[0]) | (f2bf_rne(c4[1]) << 16);
            o.y = f2bf_rne(c4[2]) | (f2bf_rne(c4[3]) << 16);
            if (row0 + row < n)
                ((uint2*)(yb + (size_t)(row0 + row) * 64))[p] = o;
        }
    }
}

// ---------------------------------------------------------------------------
// binB: one 1024-thread wg (16 waves) per bucket (round-3 form).
// ---------------------------------------------------------------------------
__global__ __launch_bounds__(1024) void binB_kernel(
    const uint2* __restrict__ slices,
    const int* __restrict__ ofs_t,
    int* __restrict__ rowptr,          // [n], end-form
    ull* __restrict__ csr,             // [E]
    int B, int nwgA, int n)
{
    __shared__ int srow[256];
    __shared__ int erow[256];
    __shared__ int red[256];
    __shared__ int hist[BROWS];
    __shared__ int curs[BROWS];
    __shared__ int ps[BROWS];
    __shared__ int s_bbase;

    const int tid  = threadIdx.x;
    const int b    = blockIdx.x;
    const int w    = tid >> 6;
    const int lane = tid & 63;

    for (int i = tid; i < nwgA; i += 1024) {
        srow[i] = ofs_t[(size_t)b * nwgA + i];
        erow[i] = ofs_t[(size_t)(b + 1) * nwgA + i];
    }
    if (tid < BROWS) hist[tid] = 0;
    __syncthreads();

    if (tid < 256) red[tid] = (tid < nwgA) ? srow[tid] : 0;
    __syncthreads();
    for (int off = 128; off > 0; off >>= 1) {
        if (tid < off) red[tid] += red[tid + off];
        __syncthreads();
    }
    if (tid == 0) s_bbase = red[0];
    __syncthreads();

    // pass 1: in-bucket row histogram
    for (int wg = w; wg < nwgA; wg += 16) {
        const int s = srow[wg];
        const int e = erow[wg];
        const uint2* run = slices + (size_t)wg * TILE;
        for (int i = s + lane; i < e; i += 64)
            atomicAdd(&hist[run[i].x & (BROWS - 1)], 1);
    }
    __syncthreads();

    int v0 = 0;
    if (tid < BROWS) { v0 = hist[tid]; ps[tid] = v0; }
    __syncthreads();
    for (int off = 1; off < BROWS; off <<= 1) {
        int t = 0;
        if (tid < BROWS && tid >= off) t = ps[tid - off];
        __syncthreads();
        if (tid < BROWS) ps[tid] += t;
        __syncthreads();
    }
    if (tid < BROWS) {
        const int excl = s_bbase + ps[tid] - v0;
        curs[tid] = excl;                       // row start
        const int r = (b << BSHIFT) + tid;
        if (r < n) rowptr[r] = excl + v0;       // row end
    }
    __syncthreads();

    // pass 2: scatter into final CSR positions (bucket-private window)
    for (int wg = w; wg < nwgA; wg += 16) {
        const int s = srow[wg];
        const int e = erow[wg];
        const uint2* run = slices + (size_t)wg * TILE;
        for (int i = s + lane; i < e; i += 64) {
            uint2 r = run[i];
            int pos = atomicAdd(&curs[r.x & (BROWS - 1)], 1);
            csr[pos] = ((ull)r.y << 32) | (r.x >> BSHIFT);
        }
    }
}

// ---------------------------------------------------------------------------
// CSR SpMM + fused column stats — round-3 pair-gather version (94us verified;
// round-4 quarter-wave widening regressed 94->170 -> frozen).
// ---------------------------------------------------------------------------
__global__ __launch_bounds__(256) void spmm_stats_kernel(
    const unsigned* __restrict__ yb,
    const int* __restrict__ rowptr,   // end-form
    const ull* __restrict__ csr,
    float* __restrict__ h,
    float* __restrict__ stats,        // [0..127]=sum, [128..255]=sumsq, zeroed
    int n)
{
    __shared__ int   rp[65];
    __shared__ float ssum[128];
    __shared__ float ssq[128];

    const int tid       = threadIdx.x;
    const int blockRow0 = blockIdx.x * 64;
    const int wv        = tid >> 6;
    const int lane      = tid & 63;
    const int half      = lane >> 5;     // which row of the pair
    const int li        = lane & 31;     // owns channels 4*li .. 4*li+3
    const int rbase     = blockRow0 + wv * 16;

    if (tid < 128) { ssum[tid] = 0.f; ssq[tid] = 0.f; }
    if (tid < 65) {
        int idx = blockRow0 + tid - 1;          // row whose END we need
        rp[tid] = (idx < 0) ? 0 : rowptr[min(idx, n - 1)];
    }
    __syncthreads();

    float s0 = 0.f, s1 = 0.f, s2 = 0.f, s3 = 0.f;
    float q0 = 0.f, q1 = 0.f, q2 = 0.f, q3 = 0.f;

    if (rbase < n) {
        for (int pr = 0; pr < 16; pr += 2) {
            const int  rA    = rbase + pr + half;     // this half's row
            const bool rowOK = rA < n;
            const int  s_    = rowOK ? rp[rA - blockRow0]     : 0;
            const int  e_    = rowOK ? rp[rA - blockRow0 + 1] : 0;
            const int  nA    = e_ - s_;
            const int  nMax  = max(nA, __shfl_xor(nA, 32));

            float a0 = 0.f, a1 = 0.f, a2 = 0.f, a3 = 0.f;
            for (int i = 0; i < nMax; i += 8) {
                ull cd[8];
#pragma unroll
                for (int j = 0; j < 8; j++) {
                    int idx = s_ + i + j;
                    int ce  = (idx < e_) ? idx : (nA ? e_ - 1 : 0);
                    cd[j] = csr[ce];
                }
                uint2 u[8];
                float v[8];
#pragma unroll
                for (int j = 0; j < 8; j++) {
                    u[j] = *(const uint2*)(yb + (size_t)(unsigned)cd[j] * 64 + 2 * li);
                    v[j] = (s_ + i + j < e_)
                               ? __uint_as_float((unsigned)(cd[j] >> 32))
                               : 0.f;
                }
#pragma unroll
                for (int j = 0; j < 8; j++) {
                    a0 += v[j] * bf_lo(u[j].x);
                    a1 += v[j] * bf_hi(u[j].x);
                    a2 += v[j] * bf_lo(u[j].y);
                    a3 += v[j] * bf_hi(u[j].y);
                }
            }

            if (rowOK) {
                *(float4*)&h[(size_t)rA * D + 4 * li] = make_float4(a0, a1, a2, a3);
                s0 += a0; s1 += a1; s2 += a2; s3 += a3;
                q0 += a0 * a0; q1 += a1 * a1; q2 += a2 * a2; q3 += a3 * a3;
            }
        }

        atomicAdd(&ssum[4 * li + 0], s0); atomicAdd(&ssum[4 * li + 1], s1);
        atomicAdd(&ssum[4 * li + 2], s2); atomicAdd(&ssum[4 * li + 3], s3);
        atomicAdd(&ssq [4 * li + 0], q0); atomicAdd(&ssq [4 * li + 1], q1);
        atomicAdd(&ssq [4 * li + 2], q2); atomicAdd(&ssq [4 * li + 3], q3);
    }
    __syncthreads();
    if (tid < 128) {
        atomicAdd(&stats[tid],       ssum[tid]);
        atomicAdd(&stats[128 + tid], ssq[tid]);
    }
}

// ---------------------------------------------------------------------------
// In-place BatchNorm apply. Linear bias cancels under BN -> omitted.
// ---------------------------------------------------------------------------
__global__ __launch_bounds__(256) void bn_apply_kernel(
    float* __restrict__ h,
    const float* __restrict__ stats,
    const float* __restrict__ gamma,
    const float* __restrict__ beta,
    int n)
{
    __shared__ float s_scale[128];
    __shared__ float s_shift[128];
    const int tid = threadIdx.x;
    if (tid < 128) {
        const float invn = 1.0f / (float)n;
        const float mean = stats[tid] * invn;
        const float var  = stats[128 + tid] * invn - mean * mean;
        const float inv  = rsqrtf(var + BN_EPS);
        const float g    = gamma[tid] * inv;
        s_scale[tid] = g;
        s_shift[tid] = beta[tid] - mean * g;
    }
    __syncthreads();

    float4* h4 = (float4*)h;
    const size_t total = (size_t)n * D / 4;
    const size_t stride = (size_t)gridDim.x * blockDim.x;
    for (size_t i = (size_t)blockIdx.x * blockDim.x + tid; i < total; i += stride) {
        float4 v = h4[i];
        const int c = (int)((i * 4) & (D - 1));
        v.x = v.x * s_scale[c]     + s_shift[c];
        v.y = v.y * s_scale[c + 1] + s_shift[c + 1];
        v.z = v.z * s_scale[c + 2] + s_shift[c + 2];
        v.w = v.w * s_scale[c + 3] + s_shift[c + 3];
        h4[i] = v;
    }
}

// ---------------------------------------------------------------------------
// Fallback (ws too small / shape mismatch): atomic SpMM + GEMM w/ stats.
// ---------------------------------------------------------------------------
__global__ __launch_bounds__(256) void spmm_atomic_kernel(
    const float* __restrict__ x,
    const int* __restrict__ esrc, const int* __restrict__ edst,
    const float* __restrict__ eval, float* __restrict__ agg, int E)
{
    int wave  = (blockIdx.x * blockDim.x + threadIdx.x) >> 6;
    int lane  = threadIdx.x & 63;
    int nwave = (gridDim.x * blockDim.x) >> 6;
    for (int e = wave; e < E; e += nwave) {
        int   s = esrc[e];
        int   d = edst[e];
        float v = eval[e];
        const float2 xv = ((const float2*)(x + (size_t)s * D))[lane];
        float* ar = agg + (size_t)d * D + lane * 2;
        atomicAdd(ar,     xv.x * v);
        atomicAdd(ar + 1, xv.y * v);
    }
}

__global__ __launch_bounds__(256) void gemm_stats_kernel(
    const float* __restrict__ A,
    const float* __restrict__ W,
    float* __restrict__ h,
    float* __restrict__ stats,
    int n)
{
    __shared__ float sW[128 * 128];
    __shared__ float sA[32][128];
    const int tid = threadIdx.x;
    const float4* W4  = (const float4*)W;
    float4*       sW4 = (float4*)sW;
#pragma unroll
    for (int i = 0; i < 16; i++) sW4[tid + 256 * i] = W4[tid + 256 * i];
    const int row0 = blockIdx.x * 32;
    const float4* A4  = (const float4*)(A + (size_t)row0 * D);
    float4*       sA4 = (float4*)&sA[0][0];
#pragma unroll
    for (int i = 0; i < 4; i++) {
        int idx = tid + 256 * i;
        sA4[idx] = ((size_t)row0 * D + (size_t)idx * 4 < (size_t)n * D)
                       ? A4[idx] : make_float4(0.f, 0.f, 0.f, 0.f);
    }
    __syncthreads();
    const int tx = tid & 31, ty = tid >> 5, c0 = tx * 4;
    float acc[4][4] = {};
    for (int k = 0; k < 128; k++) {
        const float4 w = *(const float4*)&sW[k * 128 + c0];
#pragma unroll
        for (int j = 0; j < 4; j++) {
            const float a = sA[ty + 8 * j][k];
            acc[j][0] += a * w.x; acc[j][1] += a * w.y;
            acc[j][2] += a * w.z; acc[j][3] += a * w.w;
        }
    }
#pragma unroll
    for (int j = 0; j < 4; j++) {
        const int row = row0 + ty + 8 * j;
        if (row < n)
            *(float4*)&h[(size_t)row * D + c0] =
                make_float4(acc[j][0], acc[j][1], acc[j][2], acc[j][3]);
    }
    __syncthreads();
    float* csum = &sA[0][0];
    float* csq  = csum + 128;
    if (tid < 128) { csum[tid] = 0.f; csq[tid] = 0.f; }
    __syncthreads();
#pragma unroll
    for (int c = 0; c < 4; c++) {
        float s = 0.f, q = 0.f;
#pragma unroll
        for (int j = 0; j < 4; j++) { s += acc[j][c]; q += acc[j][c] * acc[j][c]; }
        atomicAdd(&csum[c0 + c], s);
        atomicAdd(&csq[c0 + c], q);
    }
    __syncthreads();
    if (tid < 128) {
        atomicAdd(&stats[tid],       csum[tid]);
        atomicAdd(&stats[128 + tid], csq[tid]);
    }
}

// ---------------------------------------------------------------------------
extern "C" void kernel_launch(void* const* d_in, const int* in_sizes, int n_in,
                              void* d_out, int out_size, void* d_ws, size_t ws_size,
                              hipStream_t stream)
{
    const float* x     = (const float*)d_in[0];
    const int*   esrc  = (const int*)d_in[1];
    const int*   edst  = (const int*)d_in[2];
    const float* evals = (const float*)d_in[3];
    const float* W     = (const float*)d_in[4];
    // d_in[5] = bias: unused — cancels exactly under BatchNorm.
    const float* gamma = (const float*)d_in[6];
    const float* beta  = (const float*)d_in[7];
    float* out = (float*)d_out;

    const int n = in_sizes[0] / D;   // 100000
    const int E = in_sizes[1];       // 1600000

    const int B     = (n + BROWS - 1) >> BSHIFT;   // 196 buckets
    const int nwgA  = (E + TILE - 1) / TILE;       // 196 tiles
    const int ngemm = (n + 63) / 64;               // 1563 gemm blocks

    // Workspace (word-indexed):
    //   yb      [n*64]            25.6 MB (packed bf16 y = x@W)
    //   stats   [256]             zeroed (1KB memset)
    //   whiT/wloT  bf16[2*16384]  64 KB (split-W, transposed)
    //   ofs_t   [(B+1)*nwgA]      ~155 KB (transposed: [bucket][wg])
    //   rowptr  [n]
    //   (pad to even word)
    //   slices  uint2[nwgA*TILE]  12.85 MB
    //   csr     ull  [E]          12.8 MB
    unsigned*       yb     = (unsigned*)d_ws;
    float*          stats  = (float*)(yb + (size_t)n * 64);
    unsigned short* whiT   = (unsigned short*)(stats + 256);
    unsigned short* wloT   = whiT + 16384;
    int*            ofs_t  = (int*)(wloT + 16384);
    int*            rowptr = ofs_t + (size_t)(B + 1) * nwgA;
    size_t w_off = (size_t)n * 64 + 256 + 16384 /* 32768 u16 */
                 + (size_t)(B + 1) * nwgA + n;
    w_off += (w_off & 1);                          // 8B alignment
    uint2* slices = (uint2*)((unsigned*)d_ws + w_off);
    ull*   csr    = (ull*)(slices + (size_t)nwgA * TILE);
    const size_t need = (w_off + (size_t)nwgA * TILE * 2 + (size_t)E * 2) * 4;

    if (ws_size >= need && B <= 256 && nwgA <= 256) {
        hipMemsetAsync(stats, 0, 256 * 4, stream);
        wprep_kernel<<<64, 256, 0, stream>>>(W, whiT, wloT);
        phase1_kernel<<<nwgA + ngemm, 256, 0, stream>>>(
            x, whiT, wloT, yb, n, esrc, edst, evals, slices, ofs_t, B, nwgA, E);
        binB_kernel<<<B, 1024, 0, stream>>>(
            slices, ofs_t, rowptr, csr, B, nwgA, n);
        spmm_stats_kernel<<<(n + 63) / 64, 256, 0, stream>>>(
            yb, rowptr, csr, out, stats, n);
        bn_apply_kernel<<<2048, 256, 0, stream>>>(out, stats, gamma, beta, n);
    } else {
        // fallback: fp32 atomic-scatter path
        float* agg = (float*)d_ws;
        float* st  = agg + (size_t)n * D;
        hipMemsetAsync(d_ws, 0, ((size_t)n * D + 256) * 4, stream);
        spmm_atomic_kernel<<<4096, 256, 0, stream>>>(x, esrc, edst, evals, agg, E);
        gemm_stats_kernel<<<(n + 31) / 32, 256, 0, stream>>>(agg, W, out, st, n);
        bn_apply_kernel<<<2048, 256, 0, stream>>>(out, st, gamma, beta, n);
    }
}

// Round 7
// 276.723 us; speedup vs baseline: 1.3817x; 1.0538x over previous
//
#include <hip/hip_runtime.h>
#include <math.h>

// Problem constants: N=100000, E=1600000, D_IN=D_OUT=128
#define D 128
#define BSHIFT 9              // 512 dst rows per bucket
#define BROWS 512
#define TILE 8192             // edges per binA workgroup
constexpr float BN_EPS = 1e-5f;
typedef unsigned long long ull;
typedef __attribute__((ext_vector_type(8))) short short8v;   // 8 bf16 (4 VGPR)
typedef __attribute__((ext_vector_type(4))) float f32x4;     // MFMA acc

// bf16 helpers (manual, RNE) ------------------------------------------------
__device__ __forceinline__ unsigned f2bf_rne(float f) {
    unsigned u = __float_as_uint(f);
    return (u + 0x7FFFu + ((u >> 16) & 1u)) >> 16;
}
__device__ __forceinline__ float bf_lo(unsigned u) { return __uint_as_float(u << 16); }
__device__ __forceinline__ float bf_hi(unsigned u) { return __uint_as_float(u & 0xFFFF0000u); }
// split f into bf16 hi + bf16 lo (f ~ hi + lo, rel err ~2^-17)
__device__ __forceinline__ void split_bf16(float f, unsigned& hi, unsigned& lo) {
    hi = f2bf_rne(f);
    lo = f2bf_rne(f - bf_lo(hi));
}

// ---------------------------------------------------------------------------
// binAw: 1024-thread binA (coarse bucket sort) + fused wprep.
// Round-7: binA was the phase1 pole at 196 blocks x 4 waves (~3 waves/CU,
// latency-bound atomic/scatter chains). Same algorithm at 16 waves/block
// quadruples the latency-hiding wave pool. Blocks [nwgA, nwgA+16) do wprep
// (W fp32 -> transposed bf16 hi/lo for the MFMA gemm).
// ---------------------------------------------------------------------------
__global__ __launch_bounds__(1024) void binAw_kernel(
    const int* __restrict__ esrc, const int* __restrict__ edst,
    const float* __restrict__ evals,
    uint2* __restrict__ slices,        // [nwgA * TILE]
    int* __restrict__ ofs_t,           // [(B+1) * nwgA], transposed [bucket][wg]
    const float* __restrict__ W,
    unsigned short* __restrict__ whiT,
    unsigned short* __restrict__ wloT,
    int B, int nwgA, int E)
{
    __shared__ int h[256];
    __shared__ int ps[256];
    __shared__ int cur[256];
    const int tid = threadIdx.x;

    if ((int)blockIdx.x >= nwgA) {
        // ---------------- wprep: W -> whiT/wloT (transposed) ----------------
        int idx = ((int)blockIdx.x - nwgA) * 1024 + tid;
        if (idx < 128 * 128) {
            int k = idx >> 7, nn = idx & 127;
            unsigned hi, lo;
            split_bf16(W[idx], hi, lo);
            whiT[nn * 128 + k] = (unsigned short)hi;
            wloT[nn * 128 + k] = (unsigned short)lo;
        }
        return;
    }

    const int wg = blockIdx.x;
    const int e0 = wg * TILE;
    const int e1 = min(e0 + TILE, E);

    if (tid < 256) h[tid] = 0;
    __syncthreads();
    for (int e = e0 + tid; e < e1; e += 1024)
        atomicAdd(&h[edst[e] >> BSHIFT], 1);
    __syncthreads();

    int v = 0;
    if (tid < 256) { v = h[tid]; ps[tid] = v; }
    __syncthreads();
    for (int off = 1; off < 256; off <<= 1) {
        int t = 0;
        if (tid < 256 && tid >= off) t = ps[tid - off];
        __syncthreads();
        if (tid < 256 && tid >= off) ps[tid] += t;
        __syncthreads();
    }
    if (tid < B) {
        cur[tid] = ps[tid] - v;
        ofs_t[(size_t)tid * nwgA + wg] = ps[tid] - v;
    }
    if (tid == 0) ofs_t[(size_t)B * nwgA + wg] = e1 - e0;  // sentinel
    __syncthreads();

    uint2* slice = slices + (size_t)wg * TILE;
    for (int e = e0 + tid; e < e1; e += 1024) {
        int d = edst[e];
        int p = atomicAdd(&cur[d >> BSHIFT], 1);
        uint2 rec;
        rec.x = (unsigned)(d & (BROWS - 1)) | ((unsigned)esrc[e] << BSHIFT);
        rec.y = __float_as_uint(evals[e]);
        slice[p] = rec;
    }
}

// ---------------------------------------------------------------------------
// phase2: fused dispatch, 1024 threads. Blocks [0,B) run binB (verified
// round-3 logic); blocks [B, B+ngemm) run the MFMA split-bf16 gemm at
// 128 rows/block (mechanical 2x of the verified round-6 64-row kernel).
// binB depends only on binA; gemm only on wprep -> they overlap, critical
// path = max, not sum. binB blocks first in the grid.
// LDS: gemm xh/xl [128][136] u16 = 69632B (2 blocks/CU); C fp32 [128][132]
// aliases after compute; binB uses the first ~9.2KB as int scratch.
// ---------------------------------------------------------------------------
__global__ __launch_bounds__(1024) void phase2_kernel(
    const uint2* __restrict__ slices,
    const int* __restrict__ ofs_t,
    int* __restrict__ rowptr,          // [n], end-form
    ull* __restrict__ csr,             // [E]
    const float* __restrict__ A,
    const unsigned short* __restrict__ whiT,
    const unsigned short* __restrict__ wloT,
    unsigned* __restrict__ yb,
    int B, int nwgA, int n)
{
    __shared__ __align__(16) char smem[69632];
    const int tid = threadIdx.x;

    if ((int)blockIdx.x < B) {
        // ------------------------- binB -------------------------
        int* srow = (int*)smem;            // 256
        int* erow = srow + 256;            // 256
        int* red  = erow + 256;            // 256
        int* hist = red + 256;             // 512
        int* curs = hist + BROWS;          // 512
        int* ps   = curs + BROWS;          // 512
        int* s_bbase = ps + BROWS;         // 1

        const int b    = blockIdx.x;
        const int w    = tid >> 6;
        const int lane = tid & 63;

        for (int i = tid; i < nwgA; i += 1024) {
            srow[i] = ofs_t[(size_t)b * nwgA + i];
            erow[i] = ofs_t[(size_t)(b + 1) * nwgA + i];
        }
        if (tid < BROWS) hist[tid] = 0;
        __syncthreads();

        if (tid < 256) red[tid] = (tid < nwgA) ? srow[tid] : 0;
        __syncthreads();
        for (int off = 128; off > 0; off >>= 1) {
            if (tid < off) red[tid] += red[tid + off];
            __syncthreads();
        }
        if (tid == 0) *s_bbase = red[0];
        __syncthreads();

        // pass 1: in-bucket row histogram
        for (int wg = w; wg < nwgA; wg += 16) {
            const int s = srow[wg];
            const int e = erow[wg];
            const uint2* run = slices + (size_t)wg * TILE;
            for (int i = s + lane; i < e; i += 64)
                atomicAdd(&hist[run[i].x & (BROWS - 1)], 1);
        }
        __syncthreads();

        int v0 = 0;
        if (tid < BROWS) { v0 = hist[tid]; ps[tid] = v0; }
        __syncthreads();
        for (int off = 1; off < BROWS; off <<= 1) {
            int t = 0;
            if (tid < BROWS && tid >= off) t = ps[tid - off];
            __syncthreads();
            if (tid < BROWS) ps[tid] += t;
            __syncthreads();
        }
        if (tid < BROWS) {
            const int excl = *s_bbase + ps[tid] - v0;
            curs[tid] = excl;                       // row start
            const int r = (b << BSHIFT) + tid;
            if (r < n) rowptr[r] = excl + v0;       // row end
        }
        __syncthreads();

        // pass 2: scatter into final CSR positions (bucket-private window)
        for (int wg = w; wg < nwgA; wg += 16) {
            const int s = srow[wg];
            const int e = erow[wg];
            const uint2* run = slices + (size_t)wg * TILE;
            for (int i = s + lane; i < e; i += 64) {
                uint2 r = run[i];
                int pos = atomicAdd(&curs[r.x & (BROWS - 1)], 1);
                csr[pos] = ((ull)r.y << 32) | (r.x >> BSHIFT);
            }
        }
    } else {
        // ------------- gemm_pack (MFMA): y = x@W -> bf16, 128 rows -------------
        unsigned short* xh = (unsigned short*)smem;          // [128][136]
        unsigned short* xl = xh + 128 * 136;

        const int row0 = ((int)blockIdx.x - B) * 128;
        const float4* A4 = (const float4*)(A + (size_t)row0 * D);

        // stage + split x tile: 4096 float4s, 4 per thread
#pragma unroll
        for (int i = 0; i < 4; i++) {
            const int idx = tid + 1024 * i;
            const int row = idx >> 5, c4 = idx & 31;
            float4 v = (row0 + row < n) ? A4[idx]
                                        : make_float4(0.f, 0.f, 0.f, 0.f);
            unsigned h0, h1, h2, h3, l0, l1, l2, l3;
            split_bf16(v.x, h0, l0); split_bf16(v.y, h1, l1);
            split_bf16(v.z, h2, l2); split_bf16(v.w, h3, l3);
            unsigned short* ph = xh + (size_t)row * 136 + c4 * 4;
            unsigned short* pl = xl + (size_t)row * 136 + c4 * 4;
            *(uint2*)ph = make_uint2(h0 | (h1 << 16), h2 | (h3 << 16));
            *(uint2*)pl = make_uint2(l0 | (l1 << 16), l2 | (l3 << 16));
        }
        __syncthreads();

        const int wv = tid >> 6;         // 16 waves
        const int l  = tid & 63;
        const int lr = l & 15;
        const int lg = l >> 4;
        const int rowbase = (wv >> 3) * 64;   // 2 row-halves
        const int colbase = (wv & 7) * 16;    // 8 col-groups

        f32x4 acc[4];
#pragma unroll
        for (int rt = 0; rt < 4; rt++)
            acc[rt] = (f32x4){0.f, 0.f, 0.f, 0.f};

        for (int k0 = 0; k0 < 128; k0 += 32) {
            const int kf = k0 + lg * 8;
            short8v ah[4], al[4];
#pragma unroll
            for (int rt = 0; rt < 4; rt++) {
                const unsigned short* p =
                    xh + (size_t)(rowbase + 16 * rt + lr) * 136 + kf;
                const unsigned short* q =
                    xl + (size_t)(rowbase + 16 * rt + lr) * 136 + kf;
                ah[rt] = *(const short8v*)p;
                al[rt] = *(const short8v*)q;
            }
            const short8v bh = *(const short8v*)(whiT + (size_t)(colbase + lr) * 128 + kf);
            const short8v bl = *(const short8v*)(wloT + (size_t)(colbase + lr) * 128 + kf);
#pragma unroll
            for (int rt = 0; rt < 4; rt++) {
                acc[rt] = __builtin_amdgcn_mfma_f32_16x16x32_bf16(ah[rt], bh, acc[rt], 0, 0, 0);
                acc[rt] = __builtin_amdgcn_mfma_f32_16x16x32_bf16(ah[rt], bl, acc[rt], 0, 0, 0);
                acc[rt] = __builtin_amdgcn_mfma_f32_16x16x32_bf16(al[rt], bh, acc[rt], 0, 0, 0);
            }
        }
        __syncthreads();                 // all waves done reading xh/xl

        // C/D layout (verified round-6): col = colbase+lr, row = rowbase+16rt+lg*4+r
        float* Cl = (float*)smem;        // [128][132]
#pragma unroll
        for (int rt = 0; rt < 4; rt++)
#pragma unroll
            for (int r = 0; r < 4; r++) {
                const int row = rowbase + 16 * rt + lg * 4 + r;
                Cl[row * 132 + colbase + lr] = acc[rt][r];
            }
        __syncthreads();

        // pack fp32 -> bf16 pairs and store (4096 uint2, 4 per thread)
#pragma unroll
        for (int i = 0; i < 4; i++) {
            const int idx = tid + 1024 * i;
            const int row = idx >> 5, p = idx & 31;
            const float* c4 = Cl + row * 132 + p * 4;
            uint2 o;
            o.x = f2bf_rne(c4[0]) | (f2bf_rne(c4[1]) << 16);
            o.y = f2bf_rne(c4[2]) | (f2bf_rne(c4[3]) << 16);
            if (row0 + row < n)
                ((uint2*)(yb + (size_t)(row0 + row) * 64))[p] = o;
        }
    }
}

// ---------------------------------------------------------------------------
// CSR SpMM + fused column stats — round-3 pair-gather version (94us verified;
// round-4 quarter-wave widening regressed 94->170 -> frozen).
// ---------------------------------------------------------------------------
__global__ __launch_bounds__(256) void spmm_stats_kernel(
    const unsigned* __restrict__ yb,
    const int* __restrict__ rowptr,   // end-form
    const ull* __restrict__ csr,
    float* __restrict__ h,
    float* __restrict__ stats,        // [0..127]=sum, [128..255]=sumsq, zeroed
    int n)
{
    __shared__ int   rp[65];
    __shared__ float ssum[128];
    __shared__ float ssq[128];

    const int tid       = threadIdx.x;
    const int blockRow0 = blockIdx.x * 64;
    const int wv        = tid >> 6;
    const int lane      = tid & 63;
    const int half      = lane >> 5;     // which row of the pair
    const int li        = lane & 31;     // owns channels 4*li .. 4*li+3
    const int rbase     = blockRow0 + wv * 16;

    if (tid < 128) { ssum[tid] = 0.f; ssq[tid] = 0.f; }
    if (tid < 65) {
        int idx = blockRow0 + tid - 1;          // row whose END we need
        rp[tid] = (idx < 0) ? 0 : rowptr[min(idx, n - 1)];
    }
    __syncthreads();

    float s0 = 0.f, s1 = 0.f, s2 = 0.f, s3 = 0.f;
    float q0 = 0.f, q1 = 0.f, q2 = 0.f, q3 = 0.f;

    if (rbase < n) {
        for (int pr = 0; pr < 16; pr += 2) {
            const int  rA    = rbase + pr + half;     // this half's row
            const bool rowOK = rA < n;
            const int  s_    = rowOK ? rp[rA - blockRow0]     : 0;
            const int  e_    = rowOK ? rp[rA - blockRow0 + 1] : 0;
            const int  nA    = e_ - s_;
            const int  nMax  = max(nA, __shfl_xor(nA, 32));

            float a0 = 0.f, a1 = 0.f, a2 = 0.f, a3 = 0.f;
            for (int i = 0; i < nMax; i += 8) {
                ull cd[8];
#pragma unroll
                for (int j = 0; j < 8; j++) {
                    int idx = s_ + i + j;
                    int ce  = (idx < e_) ? idx : (nA ? e_ - 1 : 0);
                    cd[j] = csr[ce];
                }
                uint2 u[8];
                float v[8];
#pragma unroll
                for (int j = 0; j < 8; j++) {
                    u[j] = *(const uint2*)(yb + (size_t)(unsigned)cd[j] * 64 + 2 * li);
                    v[j] = (s_ + i + j < e_)
                               ? __uint_as_float((unsigned)(cd[j] >> 32))
                               : 0.f;
                }
#pragma unroll
                for (int j = 0; j < 8; j++) {
                    a0 += v[j] * bf_lo(u[j].x);
                    a1 += v[j] * bf_hi(u[j].x);
                    a2 += v[j] * bf_lo(u[j].y);
                    a3 += v[j] * bf_hi(u[j].y);
                }
            }

            if (rowOK) {
                *(float4*)&h[(size_t)rA * D + 4 * li] = make_float4(a0, a1, a2, a3);
                s0 += a0; s1 += a1; s2 += a2; s3 += a3;
                q0 += a0 * a0; q1 += a1 * a1; q2 += a2 * a2; q3 += a3 * a3;
            }
        }

        atomicAdd(&ssum[4 * li + 0], s0); atomicAdd(&ssum[4 * li + 1], s1);
        atomicAdd(&ssum[4 * li + 2], s2); atomicAdd(&ssum[4 * li + 3], s3);
        atomicAdd(&ssq [4 * li + 0], q0); atomicAdd(&ssq [4 * li + 1], q1);
        atomicAdd(&ssq [4 * li + 2], q2); atomicAdd(&ssq [4 * li + 3], q3);
    }
    __syncthreads();
    if (tid < 128) {
        atomicAdd(&stats[tid],       ssum[tid]);
        atomicAdd(&stats[128 + tid], ssq[tid]);
    }
}

// ---------------------------------------------------------------------------
// In-place BatchNorm apply. Linear bias cancels under BN -> omitted.
// ---------------------------------------------------------------------------
__global__ __launch_bounds__(256) void bn_apply_kernel(
    float* __restrict__ h,
    const float* __restrict__ stats,
    const float* __restrict__ gamma,
    const float* __restrict__ beta,
    int n)
{
    __shared__ float s_scale[128];
    __shared__ float s_shift[128];
    const int tid = threadIdx.x;
    if (tid < 128) {
        const float invn = 1.0f / (float)n;
        const float mean = stats[tid] * invn;
        const float var  = stats[128 + tid] * invn - mean * mean;
        const float inv  = rsqrtf(var + BN_EPS);
        const float g    = gamma[tid] * inv;
        s_scale[tid] = g;
        s_shift[tid] = beta[tid] - mean * g;
    }
    __syncthreads();

    float4* h4 = (float4*)h;
    const size_t total = (size_t)n * D / 4;
    const size_t stride = (size_t)gridDim.x * blockDim.x;
    for (size_t i = (size_t)blockIdx.x * blockDim.x + tid; i < total; i += stride) {
        float4 v = h4[i];
        const int c = (int)((i * 4) & (D - 1));
        v.x = v.x * s_scale[c]     + s_shift[c];
        v.y = v.y * s_scale[c + 1] + s_shift[c + 1];
        v.z = v.z * s_scale[c + 2] + s_shift[c + 2];
        v.w = v.w * s_scale[c + 3] + s_shift[c + 3];
        h4[i] = v;
    }
}

// ---------------------------------------------------------------------------
// Fallback (ws too small / shape mismatch): atomic SpMM + GEMM w/ stats.
// ---------------------------------------------------------------------------
__global__ __launch_bounds__(256) void spmm_atomic_kernel(
    const float* __restrict__ x,
    const int* __restrict__ esrc, const int* __restrict__ edst,
    const float* __restrict__ eval, float* __restrict__ agg, int E)
{
    int wave  = (blockIdx.x * blockDim.x + threadIdx.x) >> 6;
    int lane  = threadIdx.x & 63;
    int nwave = (gridDim.x * blockDim.x) >> 6;
    for (int e = wave; e < E; e += nwave) {
        int   s = esrc[e];
        int   d = edst[e];
        float v = eval[e];
        const float2 xv = ((const float2*)(x + (size_t)s * D))[lane];
        float* ar = agg + (size_t)d * D + lane * 2;
        atomicAdd(ar,     xv.x * v);
        atomicAdd(ar + 1, xv.y * v);
    }
}

__global__ __launch_bounds__(256) void gemm_stats_kernel(
    const float* __restrict__ A,
    const float* __restrict__ W,
    float* __restrict__ h,
    float* __restrict__ stats,
    int n)
{
    __shared__ float sW[128 * 128];
    __shared__ float sA[32][128];
    const int tid = threadIdx.x;
    const float4* W4  = (const float4*)W;
    float4*       sW4 = (float4*)sW;
#pragma unroll
    for (int i = 0; i < 16; i++) sW4[tid + 256 * i] = W4[tid + 256 * i];
    const int row0 = blockIdx.x * 32;
    const float4* A4  = (const float4*)(A + (size_t)row0 * D);
    float4*       sA4 = (float4*)&sA[0][0];
#pragma unroll
    for (int i = 0; i < 4; i++) {
        int idx = tid + 256 * i;
        sA4[idx] = ((size_t)row0 * D + (size_t)idx * 4 < (size_t)n * D)
                       ? A4[idx] : make_float4(0.f, 0.f, 0.f, 0.f);
    }
    __syncthreads();
    const int tx = tid & 31, ty = tid >> 5, c0 = tx * 4;
    float acc[4][4] = {};
    for (int k = 0; k < 128; k++) {
        const float4 w = *(const float4*)&sW[k * 128 + c0];
#pragma unroll
        for (int j = 0; j < 4; j++) {
            const float a = sA[ty + 8 * j][k];
            acc[j][0] += a * w.x; acc[j][1] += a * w.y;
            acc[j][2] += a * w.z; acc[j][3] += a * w.w;
        }
    }
#pragma unroll
    for (int j = 0; j < 4; j++) {
        const int row = row0 + ty + 8 * j;
        if (row < n)
            *(float4*)&h[(size_t)row * D + c0] =
                make_float4(acc[j][0], acc[j][1], acc[j][2], acc[j][3]);
    }
    __syncthreads();
    float* csum = &sA[0][0];
    float* csq  = csum + 128;
    if (tid < 128) { csum[tid] = 0.f; csq[tid] = 0.f; }
    __syncthreads();
#pragma unroll
    for (int c = 0; c < 4; c++) {
        float s = 0.f, q = 0.f;
#pragma unroll
        for (int j = 0; j < 4; j++) { s += acc[j][c]; q += acc[j][c] * acc[j][c]; }
        atomicAdd(&csum[c0 + c], s);
        atomicAdd(&csq[c0 + c], q);
    }
    __syncthreads();
    if (tid < 128) {
        atomicAdd(&stats[tid],       csum[tid]);
        atomicAdd(&stats[128 + tid], csq[tid]);
    }
}

// ---------------------------------------------------------------------------
extern "C" void kernel_launch(void* const* d_in, const int* in_sizes, int n_in,
                              void* d_out, int out_size, void* d_ws, size_t ws_size,
                              hipStream_t stream)
{
    const float* x     = (const float*)d_in[0];
    const int*   esrc  = (const int*)d_in[1];
    const int*   edst  = (const int*)d_in[2];
    const float* evals = (const float*)d_in[3];
    const float* W     = (const float*)d_in[4];
    // d_in[5] = bias: unused — cancels exactly under BatchNorm.
    const float* gamma = (const float*)d_in[6];
    const float* beta  = (const float*)d_in[7];
    float* out = (float*)d_out;

    const int n = in_sizes[0] / D;   // 100000
    const int E = in_sizes[1];       // 1600000

    const int B      = (n + BROWS - 1) >> BSHIFT;   // 196 buckets
    const int nwgA   = (E + TILE - 1) / TILE;       // 196 tiles
    const int ngemm  = (n + 127) / 128;             // 782 gemm blocks (128-row)

    // Workspace (word-indexed):
    //   yb      [n*64]            25.6 MB (packed bf16 y = x@W)
    //   stats   [256]             zeroed (1KB memset)
    //   whiT/wloT  bf16[2*16384]  64 KB (split-W, transposed)
    //   ofs_t   [(B+1)*nwgA]      ~155 KB (transposed: [bucket][wg])
    //   rowptr  [n]
    //   (pad to even word)
    //   slices  uint2[nwgA*TILE]  12.85 MB
    //   csr     ull  [E]          12.8 MB
    unsigned*       yb     = (unsigned*)d_ws;
    float*          stats  = (float*)(yb + (size_t)n * 64);
    unsigned short* whiT   = (unsigned short*)(stats + 256);
    unsigned short* wloT   = whiT + 16384;
    int*            ofs_t  = (int*)(wloT + 16384);
    int*            rowptr = ofs_t + (size_t)(B + 1) * nwgA;
    size_t w_off = (size_t)n * 64 + 256 + 16384 /* 32768 u16 */
                 + (size_t)(B + 1) * nwgA + n;
    w_off += (w_off & 1);                          // 8B alignment
    uint2* slices = (uint2*)((unsigned*)d_ws + w_off);
    ull*   csr    = (ull*)(slices + (size_t)nwgA * TILE);
    const size_t need = (w_off + (size_t)nwgA * TILE * 2 + (size_t)E * 2) * 4;

    if (ws_size >= need && B <= 256 && nwgA <= 256) {
        hipMemsetAsync(stats, 0, 256 * 4, stream);
        binAw_kernel<<<nwgA + 16, 1024, 0, stream>>>(
            esrc, edst, evals, slices, ofs_t, W, whiT, wloT, B, nwgA, E);
        phase2_kernel<<<B + ngemm, 1024, 0, stream>>>(
            slices, ofs_t, rowptr, csr, x, whiT, wloT, yb, B, nwgA, n);
        spmm_stats_kernel<<<(n + 63) / 64, 256, 0, stream>>>(
            yb, rowptr, csr, out, stats, n);
        bn_apply_kernel<<<2048, 256, 0, stream>>>(out, stats, gamma, beta, n);
    } else {
        // fallback: fp32 atomic-scatter path
        float* agg = (float*)d_ws;
        float* st  = agg + (size_t)n * D;
        hipMemsetAsync(d_ws, 0, ((size_t)n * D + 256) * 4, stream);
        spmm_atomic_kernel<<<4096, 256, 0, stream>>>(x, esrc, edst, evals, agg, E);
        gemm_stats_kernel<<<(n + 31) / 32, 256, 0, stream>>>(agg, W, out, st, n);
        bn_apply_kernel<<<2048, 256, 0, stream>>>(out, st, gamma, beta, n);
    }
}

// Round 9
// 276.547 us; speedup vs baseline: 1.3825x; 1.0006x over previous
//
#include <hip/hip_runtime.h>
#include <math.h>

// Problem constants: N=100000, E=1600000, D_IN=D_OUT=128
#define D 128
#define BSHIFT 9              // 512 dst rows per bucket
#define BROWS 512
#define TILE 8192             // edges per binA workgroup
constexpr float BN_EPS = 1e-5f;
typedef unsigned long long ull;
typedef __attribute__((ext_vector_type(8))) short short8v;   // 8 bf16 (4 VGPR)
typedef __attribute__((ext_vector_type(4))) float f32x4;     // MFMA acc

// bf16 helpers (manual, RNE) ------------------------------------------------
__device__ __forceinline__ unsigned f2bf_rne(float f) {
    unsigned u = __float_as_uint(f);
    return (u + 0x7FFFu + ((u >> 16) & 1u)) >> 16;
}
__device__ __forceinline__ float bf_lo(unsigned u) { return __uint_as_float(u << 16); }
__device__ __forceinline__ float bf_hi(unsigned u) { return __uint_as_float(u & 0xFFFF0000u); }
// split f into bf16 hi + bf16 lo (f ~ hi + lo, rel err ~2^-17)
__device__ __forceinline__ void split_bf16(float f, unsigned& hi, unsigned& lo) {
    hi = f2bf_rne(f);
    lo = f2bf_rne(f - bf_lo(hi));
}

// ---------------------------------------------------------------------------
// binAw: 1024-thread binA (coarse bucket sort) + fused wprep.
// ---------------------------------------------------------------------------
__global__ __launch_bounds__(1024) void binAw_kernel(
    const int* __restrict__ esrc, const int* __restrict__ edst,
    const float* __restrict__ evals,
    uint2* __restrict__ slices,        // [nwgA * TILE]
    int* __restrict__ ofs_t,           // [(B+1) * nwgA], transposed [bucket][wg]
    const float* __restrict__ W,
    unsigned short* __restrict__ whiT,
    unsigned short* __restrict__ wloT,
    int B, int nwgA, int E)
{
    __shared__ int h[256];
    __shared__ int ps[256];
    __shared__ int cur[256];
    const int tid = threadIdx.x;

    if ((int)blockIdx.x >= nwgA) {
        // ---------------- wprep: W -> whiT/wloT (transposed) ----------------
        int idx = ((int)blockIdx.x - nwgA) * 1024 + tid;
        if (idx < 128 * 128) {
            int k = idx >> 7, nn = idx & 127;
            unsigned hi, lo;
            split_bf16(W[idx], hi, lo);
            whiT[nn * 128 + k] = (unsigned short)hi;
            wloT[nn * 128 + k] = (unsigned short)lo;
        }
        return;
    }

    const int wg = blockIdx.x;
    const int e0 = wg * TILE;
    const int e1 = min(e0 + TILE, E);

    if (tid < 256) h[tid] = 0;
    __syncthreads();
    for (int e = e0 + tid; e < e1; e += 1024)
        atomicAdd(&h[edst[e] >> BSHIFT], 1);
    __syncthreads();

    int v = 0;
    if (tid < 256) { v = h[tid]; ps[tid] = v; }
    __syncthreads();
    for (int off = 1; off < 256; off <<= 1) {
        int t = 0;
        if (tid < 256 && tid >= off) t = ps[tid - off];
        __syncthreads();
        if (tid < 256 && tid >= off) ps[tid] += t;
        __syncthreads();
    }
    if (tid < B) {
        cur[tid] = ps[tid] - v;
        ofs_t[(size_t)tid * nwgA + wg] = ps[tid] - v;
    }
    if (tid == 0) ofs_t[(size_t)B * nwgA + wg] = e1 - e0;  // sentinel
    __syncthreads();

    uint2* slice = slices + (size_t)wg * TILE;
    for (int e = e0 + tid; e < e1; e += 1024) {
        int d = edst[e];
        int p = atomicAdd(&cur[d >> BSHIFT], 1);
        uint2 rec;
        rec.x = (unsigned)(d & (BROWS - 1)) | ((unsigned)esrc[e] << BSHIFT);
        rec.y = __float_as_uint(evals[e]);
        slice[p] = rec;
    }
}

// ---------------------------------------------------------------------------
// phase2: fused dispatch, 1024 threads. Blocks [0,B) run binB; blocks
// [B, B+ngemm) run the MFMA split-bf16 gemm at 128 rows/block.
// binB depends only on binA; gemm only on wprep -> overlap.
// ---------------------------------------------------------------------------
__global__ __launch_bounds__(1024) void phase2_kernel(
    const uint2* __restrict__ slices,
    const int* __restrict__ ofs_t,
    int* __restrict__ rowptr,          // [n], end-form
    ull* __restrict__ csr,             // [E]
    const float* __restrict__ A,
    const unsigned short* __restrict__ whiT,
    const unsigned short* __restrict__ wloT,
    unsigned* __restrict__ yb,
    int B, int nwgA, int n)
{
    __shared__ __align__(16) char smem[69632];
    const int tid = threadIdx.x;

    if ((int)blockIdx.x < B) {
        // ------------------------- binB -------------------------
        int* srow = (int*)smem;            // 256
        int* erow = srow + 256;            // 256
        int* red  = erow + 256;            // 256
        int* hist = red + 256;             // 512
        int* curs = hist + BROWS;          // 512
        int* ps   = curs + BROWS;          // 512
        int* s_bbase = ps + BROWS;         // 1

        const int b    = blockIdx.x;
        const int w    = tid >> 6;
        const int lane = tid & 63;

        for (int i = tid; i < nwgA; i += 1024) {
            srow[i] = ofs_t[(size_t)b * nwgA + i];
            erow[i] = ofs_t[(size_t)(b + 1) * nwgA + i];
        }
        if (tid < BROWS) hist[tid] = 0;
        __syncthreads();

        if (tid < 256) red[tid] = (tid < nwgA) ? srow[tid] : 0;
        __syncthreads();
        for (int off = 128; off > 0; off >>= 1) {
            if (tid < off) red[tid] += red[tid + off];
            __syncthreads();
        }
        if (tid == 0) *s_bbase = red[0];
        __syncthreads();

        // pass 1: in-bucket row histogram
        for (int wg = w; wg < nwgA; wg += 16) {
            const int s = srow[wg];
            const int e = erow[wg];
            const uint2* run = slices + (size_t)wg * TILE;
            for (int i = s + lane; i < e; i += 64)
                atomicAdd(&hist[run[i].x & (BROWS - 1)], 1);
        }
        __syncthreads();

        int v0 = 0;
        if (tid < BROWS) { v0 = hist[tid]; ps[tid] = v0; }
        __syncthreads();
        for (int off = 1; off < BROWS; off <<= 1) {
            int t = 0;
            if (tid < BROWS && tid >= off) t = ps[tid - off];
            __syncthreads();
            if (tid < BROWS) ps[tid] += t;
            __syncthreads();
        }
        if (tid < BROWS) {
            const int excl = *s_bbase + ps[tid] - v0;
            curs[tid] = excl;                       // row start
            const int r = (b << BSHIFT) + tid;
            if (r < n) rowptr[r] = excl + v0;       // row end
        }
        __syncthreads();

        // pass 2: scatter into final CSR positions (bucket-private window)
        for (int wg = w; wg < nwgA; wg += 16) {
            const int s = srow[wg];
            const int e = erow[wg];
            const uint2* run = slices + (size_t)wg * TILE;
            for (int i = s + lane; i < e; i += 64) {
                uint2 r = run[i];
                int pos = atomicAdd(&curs[r.x & (BROWS - 1)], 1);
                csr[pos] = ((ull)r.y << 32) | (r.x >> BSHIFT);
            }
        }
    } else {
        // ------------- gemm_pack (MFMA): y = x@W -> bf16, 128 rows -------------
        unsigned short* xh = (unsigned short*)smem;          // [128][136]
        unsigned short* xl = xh + 128 * 136;

        const int row0 = ((int)blockIdx.x - B) * 128;
        const float4* A4 = (const float4*)(A + (size_t)row0 * D);

        // stage + split x tile: 4096 float4s, 4 per thread
#pragma unroll
        for (int i = 0; i < 4; i++) {
            const int idx = tid + 1024 * i;
            const int row = idx >> 5, c4 = idx & 31;
            float4 v = (row0 + row < n) ? A4[idx]
                                        : make_float4(0.f, 0.f, 0.f, 0.f);
            unsigned h0, h1, h2, h3, l0, l1, l2, l3;
            split_bf16(v.x, h0, l0); split_bf16(v.y, h1, l1);
            split_bf16(v.z, h2, l2); split_bf16(v.w, h3, l3);
            unsigned short* ph = xh + (size_t)row * 136 + c4 * 4;
            unsigned short* pl = xl + (size_t)row * 136 + c4 * 4;
            *(uint2*)ph = make_uint2(h0 | (h1 << 16), h2 | (h3 << 16));
            *(uint2*)pl = make_uint2(l0 | (l1 << 16), l2 | (l3 << 16));
        }
        __syncthreads();

        const int wv = tid >> 6;         // 16 waves
        const int l  = tid & 63;
        const int lr = l & 15;
        const int lg = l >> 4;
        const int rowbase = (wv >> 3) * 64;   // 2 row-halves
        const int colbase = (wv & 7) * 16;    // 8 col-groups

        f32x4 acc[4];
#pragma unroll
        for (int rt = 0; rt < 4; rt++)
            acc[rt] = (f32x4){0.f, 0.f, 0.f, 0.f};

        for (int k0 = 0; k0 < 128; k0 += 32) {
            const int kf = k0 + lg * 8;
            short8v ah[4], al[4];
#pragma unroll
            for (int rt = 0; rt < 4; rt++) {
                const unsigned short* p =
                    xh + (size_t)(rowbase + 16 * rt + lr) * 136 + kf;
                const unsigned short* q =
                    xl + (size_t)(rowbase + 16 * rt + lr) * 136 + kf;
                ah[rt] = *(const short8v*)p;
                al[rt] = *(const short8v*)q;
            }
            const short8v bh = *(const short8v*)(whiT + (size_t)(colbase + lr) * 128 + kf);
            const short8v bl = *(const short8v*)(wloT + (size_t)(colbase + lr) * 128 + kf);
#pragma unroll
            for (int rt = 0; rt < 4; rt++) {
                acc[rt] = __builtin_amdgcn_mfma_f32_16x16x32_bf16(ah[rt], bh, acc[rt], 0, 0, 0);
                acc[rt] = __builtin_amdgcn_mfma_f32_16x16x32_bf16(ah[rt], bl, acc[rt], 0, 0, 0);
                acc[rt] = __builtin_amdgcn_mfma_f32_16x16x32_bf16(al[rt], bh, acc[rt], 0, 0, 0);
            }
        }
        __syncthreads();                 // all waves done reading xh/xl

        // C/D layout: col = colbase+lr, row = rowbase+16rt+lg*4+r
        float* Cl = (float*)smem;        // [128][132]
#pragma unroll
        for (int rt = 0; rt < 4; rt++)
#pragma unroll
            for (int r = 0; r < 4; r++) {
                const int row = rowbase + 16 * rt + lg * 4 + r;
                Cl[row * 132 + colbase + lr] = acc[rt][r];
            }
        __syncthreads();

        // pack fp32 -> bf16 pairs and store (4096 uint2, 4 per thread)
#pragma unroll
        for (int i = 0; i < 4; i++) {
            const int idx = tid + 1024 * i;
            const int row = idx >> 5, p = idx & 31;
            const float* c4 = Cl + row * 132 + p * 4;
            uint2 o;
            o.x = f2bf_rne(c4[0]) | (f2bf_rne(c4[1]) << 16);
            o.y = f2bf_rne(c4[2]) | (f2bf_rne(c4[3]) << 16);
            if (row0 + row < n)
                ((uint2*)(yb + (size_t)(row0 + row) * 64))[p] = o;
        }
    }
}

// ---------------------------------------------------------------------------
// CSR SpMM + fused column stats — round-9: full-residency grid, stats fixed.
//
// Round-8 FAILED (absmax 2.53): the stats atomicAdd block was gated to
// lane<32, but in the pair-gather scheme lanes>=32 (half=1) hold the ODD
// rows' accumulations -> half the stats mass dropped -> wrong BN. Fix: all
// 64 lanes atomicAdd (round-3 pattern; both halves merge via LDS atomics).
// Grid config kept from round 8: 2048 blocks = exactly one co-resident round
// (VGPR 36 -> 8 blocks/CU x 256 CU), 48-49 rows/block, 32 waves/CU vs
// round-7's grid-limited 24.4.
// ---------------------------------------------------------------------------
__global__ __launch_bounds__(256) void spmm_stats_kernel(
    const unsigned* __restrict__ yb,
    const int* __restrict__ rowptr,   // end-form
    const ull* __restrict__ csr,
    float* __restrict__ h,
    float* __restrict__ stats,        // [0..127]=sum, [128..255]=sumsq, zeroed
    int n, int nblk)
{
    __shared__ int   rp[64];
    __shared__ float ssum[128];
    __shared__ float ssq[128];

    const int tid  = threadIdx.x;
    const int b    = blockIdx.x;
    const int base = n / nblk;                  // 48
    const int rem  = n - base * nblk;           // 1696
    const int R     = base + (b < rem ? 1 : 0); // rows this block
    const int start = b * base + min(b, rem);   // first row

    const int wv   = tid >> 6;
    const int lane = tid & 63;
    const int half = lane >> 5;      // which row of the pair
    const int li   = lane & 31;      // owns channels 4*li .. 4*li+3

    if (tid < 128) { ssum[tid] = 0.f; ssq[tid] = 0.f; }
    if (tid <= R) {
        int idx = start + tid - 1;              // row whose END we need
        rp[tid] = (idx < 0) ? 0 : rowptr[idx];
    }
    __syncthreads();

    // wave wv owns local rows [lo, hi)
    const int q  = (R + 3) >> 2;
    const int lo = wv * q;
    const int hi = min(lo + q, R);

    float s0 = 0.f, s1 = 0.f, s2 = 0.f, s3 = 0.f;
    float q0 = 0.f, q1 = 0.f, q2 = 0.f, q3 = 0.f;

    for (int pr = 0; pr < hi - lo; pr += 2) {
        const int  lrw   = lo + pr + half;        // local row index
        const bool rowOK = lrw < hi;
        const int  s_    = rowOK ? rp[lrw]     : 0;
        const int  e_    = rowOK ? rp[lrw + 1] : 0;
        const int  nA    = e_ - s_;
        const int  nMax  = max(nA, __shfl_xor(nA, 32));

        float a0 = 0.f, a1 = 0.f, a2 = 0.f, a3 = 0.f;
        for (int i = 0; i < nMax; i += 8) {
            ull cd[8];
#pragma unroll
            for (int j = 0; j < 8; j++) {
                int idx = s_ + i + j;
                int ce  = (idx < e_) ? idx : (nA ? e_ - 1 : 0);
                cd[j] = csr[ce];
            }
            uint2 u[8];
            float v[8];
#pragma unroll
            for (int j = 0; j < 8; j++) {
                u[j] = *(const uint2*)(yb + (size_t)(unsigned)cd[j] * 64 + 2 * li);
                v[j] = (s_ + i + j < e_)
                           ? __uint_as_float((unsigned)(cd[j] >> 32))
                           : 0.f;
            }
#pragma unroll
            for (int j = 0; j < 8; j++) {
                a0 += v[j] * bf_lo(u[j].x);
                a1 += v[j] * bf_hi(u[j].x);
                a2 += v[j] * bf_lo(u[j].y);
                a3 += v[j] * bf_hi(u[j].y);
            }
        }

        if (rowOK) {
            const int r = start + lrw;
            *(float4*)&h[(size_t)r * D + 4 * li] = make_float4(a0, a1, a2, a3);
            s0 += a0; s1 += a1; s2 += a2; s3 += a3;
            q0 += a0 * a0; q1 += a1 * a1; q2 += a2 * a2; q3 += a3 * a3;
        }
    }

    // ALL 64 lanes: lanes>=32 carry the odd rows' sums (round-8 bug was
    // gating this to lane<32).
    atomicAdd(&ssum[4 * li + 0], s0); atomicAdd(&ssum[4 * li + 1], s1);
    atomicAdd(&ssum[4 * li + 2], s2); atomicAdd(&ssum[4 * li + 3], s3);
    atomicAdd(&ssq [4 * li + 0], q0); atomicAdd(&ssq [4 * li + 1], q1);
    atomicAdd(&ssq [4 * li + 2], q2); atomicAdd(&ssq [4 * li + 3], q3);
    __syncthreads();
    if (tid < 128) {
        atomicAdd(&stats[tid],       ssum[tid]);
        atomicAdd(&stats[128 + tid], ssq[tid]);
    }
}

// ---------------------------------------------------------------------------
// In-place BatchNorm apply. Linear bias cancels under BN -> omitted.
// ---------------------------------------------------------------------------
__global__ __launch_bounds__(256) void bn_apply_kernel(
    float* __restrict__ h,
    const float* __restrict__ stats,
    const float* __restrict__ gamma,
    const float* __restrict__ beta,
    int n)
{
    __shared__ float s_scale[128];
    __shared__ float s_shift[128];
    const int tid = threadIdx.x;
    if (tid < 128) {
        const float invn = 1.0f / (float)n;
        const float mean = stats[tid] * invn;
        const float var  = stats[128 + tid] * invn - mean * mean;
        const float inv  = rsqrtf(var + BN_EPS);
        const float g    = gamma[tid] * inv;
        s_scale[tid] = g;
        s_shift[tid] = beta[tid] - mean * g;
    }
    __syncthreads();

    float4* h4 = (float4*)h;
    const size_t total = (size_t)n * D / 4;
    const size_t stride = (size_t)gridDim.x * blockDim.x;
    for (size_t i = (size_t)blockIdx.x * blockDim.x + tid; i < total; i += stride) {
        float4 v = h4[i];
        const int c = (int)((i * 4) & (D - 1));
        v.x = v.x * s_scale[c]     + s_shift[c];
        v.y = v.y * s_scale[c + 1] + s_shift[c + 1];
        v.z = v.z * s_scale[c + 2] + s_shift[c + 2];
        v.w = v.w * s_scale[c + 3] + s_shift[c + 3];
        h4[i] = v;
    }
}

// ---------------------------------------------------------------------------
// Fallback (ws too small / shape mismatch): atomic SpMM + GEMM w/ stats.
// ---------------------------------------------------------------------------
__global__ __launch_bounds__(256) void spmm_atomic_kernel(
    const float* __restrict__ x,
    const int* __restrict__ esrc, const int* __restrict__ edst,
    const float* __restrict__ eval, float* __restrict__ agg, int E)
{
    int wave  = (blockIdx.x * blockDim.x + threadIdx.x) >> 6;
    int lane  = threadIdx.x & 63;
    int nwave = (gridDim.x * blockDim.x) >> 6;
    for (int e = wave; e < E; e += nwave) {
        int   s = esrc[e];
        int   d = edst[e];
        float v = eval[e];
        const float2 xv = ((const float2*)(x + (size_t)s * D))[lane];
        float* ar = agg + (size_t)d * D + lane * 2;
        atomicAdd(ar,     xv.x * v);
        atomicAdd(ar + 1, xv.y * v);
    }
}

__global__ __launch_bounds__(256) void gemm_stats_kernel(
    const float* __restrict__ A,
    const float* __restrict__ W,
    float* __restrict__ h,
    float* __restrict__ stats,
    int n)
{
    __shared__ float sW[128 * 128];
    __shared__ float sA[32][128];
    const int tid = threadIdx.x;
    const float4* W4  = (const float4*)W;
    float4*       sW4 = (float4*)sW;
#pragma unroll
    for (int i = 0; i < 16; i++) sW4[tid + 256 * i] = W4[tid + 256 * i];
    const int row0 = blockIdx.x * 32;
    const float4* A4  = (const float4*)(A + (size_t)row0 * D);
    float4*       sA4 = (float4*)&sA[0][0];
#pragma unroll
    for (int i = 0; i < 4; i++) {
        int idx = tid + 256 * i;
        sA4[idx] = ((size_t)row0 * D + (size_t)idx * 4 < (size_t)n * D)
                       ? A4[idx] : make_float4(0.f, 0.f, 0.f, 0.f);
    }
    __syncthreads();
    const int tx = tid & 31, ty = tid >> 5, c0 = tx * 4;
    float acc[4][4] = {};
    for (int k = 0; k < 128; k++) {
        const float4 w = *(const float4*)&sW[k * 128 + c0];
#pragma unroll
        for (int j = 0; j < 4; j++) {
            const float a = sA[ty + 8 * j][k];
            acc[j][0] += a * w.x; acc[j][1] += a * w.y;
            acc[j][2] += a * w.z; acc[j][3] += a * w.w;
        }
    }
#pragma unroll
    for (int j = 0; j < 4; j++) {
        const int row = row0 + ty + 8 * j;
        if (row < n)
            *(float4*)&h[(size_t)row * D + c0] =
                make_float4(acc[j][0], acc[j][1], acc[j][2], acc[j][3]);
    }
    __syncthreads();
    float* csum = &sA[0][0];
    float* csq  = csum + 128;
    if (tid < 128) { csum[tid] = 0.f; csq[tid] = 0.f; }
    __syncthreads();
#pragma unroll
    for (int c = 0; c < 4; c++) {
        float s = 0.f, q = 0.f;
#pragma unroll
        for (int j = 0; j < 4; j++) { s += acc[j][c]; q += acc[j][c] * acc[j][c]; }
        atomicAdd(&csum[c0 + c], s);
        atomicAdd(&csq[c0 + c], q);
    }
    __syncthreads();
    if (tid < 128) {
        atomicAdd(&stats[tid],       csum[tid]);
        atomicAdd(&stats[128 + tid], csq[tid]);
    }
}

// ---------------------------------------------------------------------------
extern "C" void kernel_launch(void* const* d_in, const int* in_sizes, int n_in,
                              void* d_out, int out_size, void* d_ws, size_t ws_size,
                              hipStream_t stream)
{
    const float* x     = (const float*)d_in[0];
    const int*   esrc  = (const int*)d_in[1];
    const int*   edst  = (const int*)d_in[2];
    const float* evals = (const float*)d_in[3];
    const float* W     = (const float*)d_in[4];
    // d_in[5] = bias: unused — cancels exactly under BatchNorm.
    const float* gamma = (const float*)d_in[6];
    const float* beta  = (const float*)d_in[7];
    float* out = (float*)d_out;

    const int n = in_sizes[0] / D;   // 100000
    const int E = in_sizes[1];       // 1600000

    const int B      = (n + BROWS - 1) >> BSHIFT;   // 196 buckets
    const int nwgA   = (E + TILE - 1) / TILE;       // 196 tiles
    const int ngemm  = (n + 127) / 128;             // 782 gemm blocks (128-row)
    const int nspmm  = 2048;                        // full-residency spmm grid

    // Workspace (word-indexed):
    //   yb      [n*64]            25.6 MB (packed bf16 y = x@W)
    //   stats   [256]             zeroed (1KB memset)
    //   whiT/wloT  bf16[2*16384]  64 KB (split-W, transposed)
    //   ofs_t   [(B+1)*nwgA]      ~155 KB (transposed: [bucket][wg])
    //   rowptr  [n]
    //   (pad to even word)
    //   slices  uint2[nwgA*TILE]  12.85 MB
    //   csr     ull  [E]          12.8 MB
    unsigned*       yb     = (unsigned*)d_ws;
    float*          stats  = (float*)(yb + (size_t)n * 64);
    unsigned short* whiT   = (unsigned short*)(stats + 256);
    unsigned short* wloT   = whiT + 16384;
    int*            ofs_t  = (int*)(wloT + 16384);
    int*            rowptr = ofs_t + (size_t)(B + 1) * nwgA;
    size_t w_off = (size_t)n * 64 + 256 + 16384 /* 32768 u16 */
                 + (size_t)(B + 1) * nwgA + n;
    w_off += (w_off & 1);                          // 8B alignment
    uint2* slices = (uint2*)((unsigned*)d_ws + w_off);
    ull*   csr    = (ull*)(slices + (size_t)nwgA * TILE);
    const size_t need = (w_off + (size_t)nwgA * TILE * 2 + (size_t)E * 2) * 4;

    if (ws_size >= need && B <= 256 && nwgA <= 256 && n >= nspmm) {
        hipMemsetAsync(stats, 0, 256 * 4, stream);
        binAw_kernel<<<nwgA + 16, 1024, 0, stream>>>(
            esrc, edst, evals, slices, ofs_t, W, whiT, wloT, B, nwgA, E);
        phase2_kernel<<<B + ngemm, 1024, 0, stream>>>(
            slices, ofs_t, rowptr, csr, x, whiT, wloT, yb, B, nwgA, n);
        spmm_stats_kernel<<<nspmm, 256, 0, stream>>>(
            yb, rowptr, csr, out, stats, n, nspmm);
        bn_apply_kernel<<<2048, 256, 0, stream>>>(out, stats, gamma, beta, n);
    } else {
        // fallback: fp32 atomic-scatter path
        float* agg = (float*)d_ws;
        float* st  = agg + (size_t)n * D;
        hipMemsetAsync(d_ws, 0, ((size_t)n * D + 256) * 4, stream);
        spmm_atomic_kernel<<<4096, 256, 0, stream>>>(x, esrc, edst, evals, agg, E);
        gemm_stats_kernel<<<(n + 31) / 32, 256, 0, stream>>>(agg, W, out, st, n);
        bn_apply_kernel<<<2048, 256, 0, stream>>>(out, st, gamma, beta, n);
    }
}